// Round 5
// baseline (530.240 us; speedup 1.0000x reference)
//
#include <hip/hip_runtime.h>
#include <cstdint>

// Single mega-kernel, plain launch (256 blocks x 256 threads = 1 block/CU,
// forced by 83.2KB LDS), hand-rolled grid barrier with explicit device-scope
// fences (cross-XCD L2 coherence). Phases identical to R2:
//  Z  zero WadjT/Adn/wsum
//  0  XW = pos@W1 + edge scatter (atomics) + wsum
//  1  GCN+relu -> H, fused s1 softmax (16 nodes/blk)
//  2  AS1 (wave/node, 4 iters) + dflat
//  3  pool1 (blks 0..15) + x1 (blks 64..191)
//  4  conv2 (blks 0..127)
//  5  s2 + pool2 fused (blks 0..15)
//  6  x3 (0..127) + agg (128..255) + losses (blk 255)
//  7  conv3 -> out (0..127)

#define WS_WADJT 0
#define WS_ADN   1048576
#define WS_WSUM  2097152
#define WS_XW    2101248
#define WS_H     4198400
#define WS_S1    6295552
#define WS_TMP   6557696
#define WS_DFLAT 6819840
#define WS_ADJ1  6823936
#define WS_X1    6889472
#define WS_X2    7413760
#define WS_X3    7938048
#define WS_S2    8200192
#define WS_ADJ2  8232960
#define WS_SCAL  8249344
#define WS_BAR   8249408   // 2 ints: arrive counter, generation

#define NBLK 256

// Sense-reversing grid barrier. Entry __syncthreads drains the block's stores
// to L2 (compiler emits vmcnt(0) before s_barrier); tid0's threadfence does
// agent-scope release (L2 writeback) / acquire (invalidate). One block per CU
// so tid0's L1 fence covers the whole block.
__device__ __forceinline__ void gridBarrier(int* cnt, int* gen) {
  __syncthreads();
  if (threadIdx.x == 0) {
    __threadfence();   // release: flush this XCD's dirty lines
    int g = __hip_atomic_load(gen, __ATOMIC_RELAXED, __HIP_MEMORY_SCOPE_AGENT);
    int a = __hip_atomic_fetch_add(cnt, 1, __ATOMIC_ACQ_REL, __HIP_MEMORY_SCOPE_AGENT);
    if (a == NBLK - 1) {
      __hip_atomic_store(cnt, 0, __ATOMIC_RELAXED, __HIP_MEMORY_SCOPE_AGENT);
      __hip_atomic_fetch_add(gen, 1, __ATOMIC_ACQ_REL, __HIP_MEMORY_SCOPE_AGENT);
    } else {
      while (__hip_atomic_load(gen, __ATOMIC_RELAXED, __HIP_MEMORY_SCOPE_AGENT) == g) {}
    }
    __threadfence();   // acquire: invalidate stale lines before phase reads
  }
  __syncthreads();
}

// 256-thread (4-wave) block reduction, red[4]
__device__ __forceinline__ float blockRedSum4(float v, float* red) {
  #pragma unroll
  for (int m = 32; m; m >>= 1) v += __shfl_xor(v, m);
  __syncthreads();
  if ((threadIdx.x & 63) == 0) red[threadIdx.x >> 6] = v;
  __syncthreads();
  return red[0] + red[1] + red[2] + red[3];
}

__global__ __launch_bounds__(256) void k_mega(
    const float* __restrict__ pos, const int* __restrict__ ei, const float* __restrict__ ea,
    const float* __restrict__ W1, const float* __restrict__ b1,
    const float* __restrict__ p1W, const float* __restrict__ p1b,
    const float* __restrict__ c2rW, const float* __restrict__ c2rb, const float* __restrict__ c2sW,
    const float* __restrict__ p2W, const float* __restrict__ p2b,
    const float* __restrict__ c3rW, const float* __restrict__ c3rb, const float* __restrict__ c3sW,
    float* __restrict__ ws, float* __restrict__ out)
{
  int* bcnt = (int*)(ws + WS_BAR);
  int* bgen = (int*)(ws + WS_BAR) + 1;
  __shared__ float sm[20800];  // 83.2 KB, sized for conv2 phase (5 x 64x65)
  int tid = threadIdx.x, blk = blockIdx.x;
  int gtid = blk * 256 + tid;

  // ---------------- Phase Z: zero WadjT + Adn + wsum (2101248 floats)
  {
    float4* p = (float4*)ws;
    for (int i = gtid; i < 525312; i += 65536) p[i] = make_float4(0.f, 0.f, 0.f, 0.f);
  }
  gridBarrier(bcnt, bgen);

  // ---------------- Phase 0: XW = pos @ W1 ; edge scatter + wsum
  {
    for (int i = tid; i < 4096; i += 256) sm[i] = W1[i];
    __syncthreads();
    int col = tid & 63;
    for (int pass = 0; pass < 32; ++pass) {
      int row = blk * 128 + pass * 4 + (tid >> 6);
      const float* a = pos + (size_t)row * 64;
      float acc = 0.f;
      #pragma unroll 8
      for (int k = 0; k < 64; ++k) acc += a[k] * sm[k * 64 + col];
      ws[WS_XW + (size_t)row * 64 + col] = acc;
    }
    // one edge per thread (E = 65536 = gridDim*blockDim)
    int e = gtid;
    int s = ei[e], d = ei[65536 + e];
    int g = s >> 8, r = s & 255, c = d & 255;
    float w = ea[e];
    atomicAdd(&ws[WS_WADJT + (size_t)(((g << 8) + c) << 8) + r], w);
    atomicAdd(&ws[WS_ADN + (size_t)(((g << 8) + r) << 8) + c], 1.0f);
    atomicAdd(&ws[WS_WSUM + (g << 8) + c], w);
  }
  gridBarrier(bcnt, bgen);

  // ---------------- Phase 1: GCN + relu -> H ; fused s1 (16 nodes per block)
  {
    float* sW = sm;              // 4096 (p1W)
    float* dinvL = sm + 4096;    // 256
    float* pL = sm + 4352;       // 256
    float* red4 = sm + 4608;     // 256
    float* xm = sm + 4864;       // 64
    int* iL = (int*)(sm + 4928); // 256 ints
    int* wcnt = (int*)(sm + 5184); // 4 ints
    int g = blk >> 4;
    for (int i = tid; i < 4096; i += 256) sW[i] = p1W[i];
    dinvL[tid] = rsqrtf(ws[WS_WSUM + (g << 8) + tid] + 1.0f);
    __syncthreads();
    int w = tid >> 6, lane = tid & 63;
    float bb = b1[tid & 63];
    for (int it = 0; it < 16; ++it) {
      int n = blk * 16 + it;
      int cc = n & 255;
      float dn = dinvL[cc];
      float pv = ws[WS_WADJT + (size_t)n * 256 + tid] * dinvL[tid] * dn;
      if (tid == cc) pv += dn * dn;
      bool act = (pv != 0.f);
      unsigned long long mask = __ballot(act);
      int wpos = (int)__popcll(mask & ((1ull << lane) - 1ull));
      if (lane == 0) wcnt[w] = (int)__popcll(mask);
      __syncthreads();
      int base = 0;
      #pragma unroll
      for (int i = 0; i < 4; ++i) base += (i < w) ? wcnt[i] : 0;
      int na = wcnt[0] + wcnt[1] + wcnt[2] + wcnt[3];
      if (act) { iL[base + wpos] = tid; pL[base + wpos] = pv; }
      __syncthreads();
      const float* xg = ws + WS_XW + (size_t)g * 131072;
      float acc0 = 0.f, acc1 = 0.f;
      for (int i = 0; i < na; ++i) {
        int r = iL[i];
        float p = pL[i];
        acc0 += p * xg[(size_t)r * 512 + tid];
        acc1 += p * xg[(size_t)r * 512 + 256 + tid];
      }
      acc0 = fmaxf(acc0 + bb, 0.f);
      acc1 = fmaxf(acc1 + bb, 0.f);
      float* hp = ws + WS_H + (size_t)n * 512;
      hp[tid] = acc0;
      hp[256 + tid] = acc1;
      red4[w * 64 + (tid & 63)] = acc0 + acc1;
      __syncthreads();
      if (tid < 64) {
        xm[tid] = 0.125f * (red4[tid] + red4[64 + tid] + red4[128 + tid] + red4[192 + tid]);
        float a = p1b[tid];
        #pragma unroll 4
        for (int kq = 0; kq < 64; ++kq) a += xm[kq] * sW[kq * 64 + tid];
        float v = tanhf(a);
        float mx = v;
        #pragma unroll
        for (int m = 32; m; m >>= 1) mx = fmaxf(mx, __shfl_xor(mx, m));
        float e = __expf(v - mx);
        float se = e;
        #pragma unroll
        for (int m = 32; m; m >>= 1) se += __shfl_xor(se, m);
        ws[WS_S1 + (size_t)n * 64 + tid] = e / se;
      }
      __syncthreads();
    }
  }
  gridBarrier(bcnt, bgen);

  // ---------------- Phase 2: AS1 = Adn @ S1 (wave per node, 4 iterations) + dflat
  {
    float* aL = sm;                // 1024
    int* iLa = (int*)(sm + 1024);  // 1024 ints
    int w = tid >> 6, lane = tid & 63;
    for (int nit = 0; nit < 4; ++nit) {
      int n = nit * 1024 + blk * 4 + w;
      int g = n >> 8;
      float4 av = *(const float4*)(ws + WS_ADN + (size_t)n * 256 + lane * 4);
      float rs = av.x + av.y + av.z + av.w;
      #pragma unroll
      for (int m = 32; m; m >>= 1) rs += __shfl_xor(rs, m);
      if (lane == 0) ws[WS_DFLAT + n] = rs;
      float avv[4] = {av.x, av.y, av.z, av.w};
      unsigned long long below = (1ull << lane) - 1ull;
      int base = 0;
      #pragma unroll
      for (int q = 0; q < 4; ++q) {
        bool act = (avv[q] != 0.f);
        unsigned long long mask = __ballot(act);
        if (act) {
          int p = base + (int)__popcll(mask & below);
          iLa[w * 256 + p] = lane * 4 + q;
          aL[w * 256 + p] = avv[q];
        }
        base += (int)__popcll(mask);
      }
      int na = base;
      float acc = 0.f;
      const float* S1g = ws + WS_S1 + ((size_t)g << 8) * 64;
      for (int i = 0; i < na; ++i) {
        int m = iLa[w * 256 + i];
        float a = aL[w * 256 + i];
        acc += a * S1g[(size_t)m * 64 + lane];
      }
      ws[WS_TMP + (size_t)n * 64 + lane] = acc;
    }
  }
  gridBarrier(bcnt, bgen);

  // ---------------- Phase 3: pool1 (blks 0..15) + x1 (blks 64..191)
  if (blk < 16) {
    int b = blk;
    float* S1c = sm;          // 2048
    float* Tc = sm + 2048;    // 2048
    float* prs = sm + 4096;   // 64*5 = 320
    float* diagL = sm + 4416; // 64
    float* dd = sm + 4480;    // 64
    float* red = sm + 4544;   // 4
    const float* Sb = ws + WS_S1 + (size_t)b * 16384;
    const float* Tb = ws + WS_TMP + (size_t)b * 16384;
    int k = tid >> 2, j0 = (tid & 3) * 16;
    float accA[16], accS[16];
    #pragma unroll
    for (int q = 0; q < 16; ++q) { accA[q] = 0.f; accS[q] = 0.f; }
    for (int n0 = 0; n0 < 256; n0 += 32) {
      __syncthreads();
      for (int i = tid; i < 2048; i += 256) { S1c[i] = Sb[n0 * 64 + i]; Tc[i] = Tb[n0 * 64 + i]; }
      __syncthreads();
      for (int i = 0; i < 32; ++i) {
        float sk = S1c[i * 64 + k];
        const float4* tp = (const float4*)(Tc + i * 64 + j0);
        const float4* sp = (const float4*)(S1c + i * 64 + j0);
        #pragma unroll
        for (int q4 = 0; q4 < 4; ++q4) {
          float4 tv = tp[q4], sv = sp[q4];
          accA[q4 * 4 + 0] += sk * tv.x; accA[q4 * 4 + 1] += sk * tv.y;
          accA[q4 * 4 + 2] += sk * tv.z; accA[q4 * 4 + 3] += sk * tv.w;
          accS[q4 * 4 + 0] += sk * sv.x; accS[q4 * 4 + 1] += sk * sv.y;
          accS[q4 * 4 + 2] += sk * sv.z; accS[q4 * 4 + 3] += sk * sv.w;
        }
      }
    }
    float num = 0.f, fro2 = 0.f, rsp = 0.f;
    #pragma unroll
    for (int q = 0; q < 16; ++q) { rsp += accA[q]; fro2 += accS[q] * accS[q]; }
    #pragma unroll
    for (int q = 0; q < 16; ++q)
      if (j0 + q == k) { num = accA[q]; diagL[k] = accA[q]; }
    prs[k * 5 + (tid & 3)] = rsp;
    __syncthreads();
    if (tid < 64) {
      float rs = prs[tid * 5] + prs[tid * 5 + 1] + prs[tid * 5 + 2] + prs[tid * 5 + 3];
      dd[tid] = sqrtf(fmaxf(rs - diagL[tid], 0.f)) + 1e-15f;
    }
    float denp;
    {
      const float* s = Sb + tid * 64;
      float qq = 0.f;
      for (int kk = 0; kk < 64; kk += 4) {
        float4 v = *(const float4*)(s + kk);
        qq += v.x * v.x + v.y * v.y + v.z * v.z + v.w * v.w;
      }
      denp = qq * ws[WS_DFLAT + (b << 8) + tid];
    }
    float numT = blockRedSum4(num, red);
    float denT = blockRedSum4(denp, red);
    float froT = sqrtf(blockRedSum4(fro2, red));
    float inv_fro = 1.f / froT;
    float osum = 0.f;
    #pragma unroll
    for (int q = 0; q < 16; ++q) {
      float v = accS[q] * inv_fro - ((j0 + q) == k ? 0.125f : 0.f);
      osum += v * v;
    }
    float orT = blockRedSum4(osum, red);
    float* adj = ws + WS_ADJ1 + (size_t)b * 4096;
    float dk = dd[k];
    #pragma unroll
    for (int q = 0; q < 16; ++q) {
      int j = j0 + q;
      adj[k * 64 + j] = (k == j) ? 0.f : accA[q] / (dk * dd[j]);
    }
    if (tid == 0) {
      ws[WS_SCAL + b] = numT / denT;
      ws[WS_SCAL + 16 + b] = sqrtf(orT);
    }
  } else if (blk >= 64 && blk < 192) {
    // x1[b,t,k,h] = sum_n S1[b,n,k] h[b,n,t,h]
    int bt = blk - 64;
    int b = bt >> 3, t = bt & 7;
    int hc = tid & 63, kb = (tid >> 6) * 16;
    float* sS = sm;          // 2048
    float* sX = sm + 2048;   // 2048
    float acc[16];
    #pragma unroll
    for (int q = 0; q < 16; ++q) acc[q] = 0.f;
    for (int n0 = 0; n0 < 256; n0 += 32) {
      __syncthreads();
      for (int idx = tid; idx < 2048; idx += 256) {
        int i = idx >> 6, c = idx & 63;
        sS[idx] = ws[WS_S1 + ((size_t)((b << 8) + n0 + i)) * 64 + c];
        sX[idx] = ws[WS_H + ((size_t)((b << 8) + n0 + i)) * 512 + t * 64 + c];
      }
      __syncthreads();
      for (int i = 0; i < 32; ++i) {
        float xv = sX[i * 64 + hc];
        #pragma unroll
        for (int q = 0; q < 16; ++q) acc[q] += sS[i * 64 + kb + q] * xv;
      }
    }
    #pragma unroll
    for (int q = 0; q < 16; ++q)
      ws[WS_X1 + ((size_t)bt * 64 + kb + q) * 64 + hc] = acc[q];
  }
  gridBarrier(bcnt, bgen);

  // ---------------- Phase 4: conv2 (blks 0..127)
  if (blk < 128) {
    int bt = blk;
    int b = bt >> 3;
    float* sA = sm;
    float* sX = sm + 4160;
    float* sY = sm + 8320;
    float* sWr = sm + 12480;
    float* sWs = sm + 16640;
    for (int idx = tid; idx < 4096; idx += 256) {
      int r = idx >> 6, c = idx & 63;
      sA[r * 65 + c] = ws[WS_ADJ1 + (size_t)b * 4096 + idx];
      sX[r * 65 + c] = ws[WS_X1 + (size_t)bt * 4096 + idx];
      sWr[r * 65 + c] = c2rW[idx];
      sWs[r * 65 + c] = c2sW[idx];
    }
    __syncthreads();
    int n = tid >> 2, h0 = (tid & 3) * 16;
    float acc[16];
    #pragma unroll
    for (int q = 0; q < 16; ++q) acc[q] = 0.f;
    for (int m = 0; m < 64; ++m) {
      float a = sA[n * 65 + m];
      #pragma unroll
      for (int q = 0; q < 16; ++q) acc[q] += a * sX[m * 65 + h0 + q];
    }
    #pragma unroll
    for (int q = 0; q < 16; ++q) sY[n * 65 + h0 + q] = acc[q];
    __syncthreads();
    #pragma unroll
    for (int q = 0; q < 16; ++q) acc[q] = c2rb[h0 + q];
    for (int m = 0; m < 64; ++m) {
      float y = sY[n * 65 + m], x = sX[n * 65 + m];
      #pragma unroll
      for (int q = 0; q < 16; ++q)
        acc[q] += y * sWr[m * 65 + h0 + q] + x * sWs[m * 65 + h0 + q];
    }
    #pragma unroll
    for (int q = 0; q < 16; ++q)
      ws[WS_X2 + (size_t)bt * 4096 + n * 64 + h0 + q] = fmaxf(acc[q], 0.f);
  }
  gridBarrier(bcnt, bgen);

  // ---------------- Phase 5: s2 (in LDS) + pool2 fused (blks 0..15)
  if (blk < 16) {
    int b = blk;
    float* xmL = sm;            // 4096
    float* sS2 = sm + 4096;     // 64*33 = 2112
    float* sA2 = sm + 6208;     // 64*65 = 4160
    float* sT  = sm + 10368;    // 64*33 = 2112
    float* oaL = sm + 12480;    // 32*33 = 1056
    float* ssL = sm + 13536;    // 32*33 = 1056
    float* sdf = sm + 14592;    // 64
    float* ddL = sm + 14656;    // 32
    float* red = sm + 14688;    // 4
    float* sp2W = sm + 14692;   // 2048
    for (int idx = tid; idx < 4096; idx += 256)
      sA2[(idx >> 6) * 65 + (idx & 63)] = ws[WS_ADJ1 + (size_t)b * 4096 + idx];
    for (int idx = tid; idx < 2048; idx += 256) sp2W[idx] = p2W[idx];
    for (int idx = tid; idx < 4096; idx += 256) {
      int n = idx >> 6, f = idx & 63;
      float s = 0.f;
      #pragma unroll
      for (int t = 0; t < 8; ++t)
        s += ws[WS_X2 + ((size_t)(b * 8 + t) * 64 + n) * 64 + f];
      xmL[idx] = s * 0.125f;
    }
    __syncthreads();
    {
      int n = tid >> 2, jq = (tid & 3) * 8;
      float acc[8];
      #pragma unroll
      for (int q = 0; q < 8; ++q) acc[q] = p2b[jq + q];
      for (int kq = 0; kq < 64; ++kq) {
        float v = xmL[n * 64 + kq];
        #pragma unroll
        for (int q = 0; q < 8; ++q) acc[q] += v * sp2W[kq * 32 + jq + q];
      }
      float vq[8];
      float mx = -1e30f;
      #pragma unroll
      for (int q = 0; q < 8; ++q) { vq[q] = tanhf(acc[q]); mx = fmaxf(mx, vq[q]); }
      mx = fmaxf(mx, __shfl_xor(mx, 1));
      mx = fmaxf(mx, __shfl_xor(mx, 2));
      float eq[8], se = 0.f;
      #pragma unroll
      for (int q = 0; q < 8; ++q) { eq[q] = __expf(vq[q] - mx); se += eq[q]; }
      se += __shfl_xor(se, 1);
      se += __shfl_xor(se, 2);
      float inv = 1.f / se;
      #pragma unroll
      for (int q = 0; q < 8; ++q) {
        float e = eq[q] * inv;
        sS2[n * 33 + jq + q] = e;
        ws[WS_S2 + (size_t)(b * 64 + n) * 32 + jq + q] = e;
      }
    }
    __syncthreads();
    if (tid < 64) {
      float s = 0.f;
      for (int m = 0; m < 64; ++m) s += sA2[tid * 65 + m];
      sdf[tid] = s;
    }
    {
      int n = tid >> 2, j0 = (tid & 3) * 8;
      float acc[8];
      #pragma unroll
      for (int q = 0; q < 8; ++q) acc[q] = 0.f;
      for (int m = 0; m < 64; ++m) {
        float a = sA2[n * 65 + m];
        #pragma unroll
        for (int q = 0; q < 8; ++q) acc[q] += a * sS2[m * 33 + j0 + q];
      }
      #pragma unroll
      for (int q = 0; q < 8; ++q) sT[n * 33 + j0 + q] = acc[q];
    }
    float accD = 0.f;
    if (tid < 64) {
      float t = 0.f;
      for (int q = 0; q < 32; ++q) { float v = sS2[tid * 33 + q]; t += v * v; }
      accD = t;
    }
    __syncthreads();
    if (tid < 64) accD *= sdf[tid];
    int k = tid >> 3, j0 = (tid & 7) * 4;
    float accA[4], accS[4];
    #pragma unroll
    for (int q = 0; q < 4; ++q) { accA[q] = 0.f; accS[q] = 0.f; }
    for (int n = 0; n < 64; ++n) {
      float sk = sS2[n * 33 + k];
      #pragma unroll
      for (int q = 0; q < 4; ++q) {
        accA[q] += sk * sT[n * 33 + j0 + q];
        accS[q] += sk * sS2[n * 33 + j0 + q];
      }
    }
    #pragma unroll
    for (int q = 0; q < 4; ++q) {
      oaL[k * 33 + j0 + q] = accA[q];
      ssL[k * 33 + j0 + q] = accS[q];
    }
    float fro2p = 0.f;
    #pragma unroll
    for (int q = 0; q < 4; ++q) fro2p += accS[q] * accS[q];
    __syncthreads();
    float num = 0.f, trs = 0.f;
    if (tid < 32) {
      num = oaL[tid * 33 + tid];
      trs = ssL[tid * 33 + tid];
      float rs = 0.f;
      for (int j = 0; j < 32; ++j) rs += oaL[tid * 33 + j];
      ddL[tid] = sqrtf(fmaxf(rs - num, 0.f)) + 1e-15f;
    }
    float numT = blockRedSum4(num, red);
    float denT = blockRedSum4(accD, red);
    float froT = sqrtf(blockRedSum4(fro2p, red));
    float trT = blockRedSum4(trs, red);
    __syncthreads();
    {
      int idx = tid * 4, kk = idx >> 5, jj = idx & 31;
      float dk = ddL[kk];
      float* a2 = ws + WS_ADJ2 + (size_t)b * 1024;
      #pragma unroll
      for (int q = 0; q < 4; ++q) {
        int j = jj + q;
        a2[kk * 32 + j] = (kk == j) ? 0.f : oaL[kk * 33 + j] / (dk * ddL[j]);
      }
    }
    if (tid == 0) {
      ws[WS_SCAL + 32 + b] = numT / denT;
      ws[WS_SCAL + 48 + b] = sqrtf(fmaxf(2.f - 2.f * trT / (5.656854249f * froT), 0.f));
    }
  }
  gridBarrier(bcnt, bgen);

  // ---------------- Phase 6: x3 (blks 0..127) + agg (blks 128..255) + losses
  if (blk < 128) {
    int bt = blk, b = bt >> 3;
    float* sX = sm;           // 64*65
    float* sS = sm + 4160;    // 64*33
    for (int idx = tid; idx < 4096; idx += 256)
      sX[(idx >> 6) * 65 + (idx & 63)] = ws[WS_X2 + (size_t)bt * 4096 + idx];
    for (int idx = tid; idx < 2048; idx += 256)
      sS[(idx >> 5) * 33 + (idx & 31)] = ws[WS_S2 + (size_t)b * 2048 + idx];
    __syncthreads();
    int k = tid >> 3, h0 = (tid & 7) * 8;
    float acc[8];
    #pragma unroll
    for (int q = 0; q < 8; ++q) acc[q] = 0.f;
    for (int n = 0; n < 64; ++n) {
      float sv = sS[n * 33 + k];
      #pragma unroll
      for (int q = 0; q < 8; ++q) acc[q] += sv * sX[n * 65 + h0 + q];
    }
    #pragma unroll
    for (int q = 0; q < 8; ++q)
      ws[WS_X3 + (size_t)bt * 2048 + k * 64 + h0 + q] = acc[q];
  } else {
    int rb = blk - 128;
    int b = rb >> 3, sub = rb & 7;
    float* sS = sm;  // 64*33
    for (int idx = tid; idx < 2048; idx += 256)
      sS[(idx >> 5) * 33 + (idx & 31)] = ws[WS_S2 + (size_t)b * 2048 + idx];
    __syncthreads();
    for (int jt = 0; jt < 4; ++jt) {
      int n0 = (sub * 4 + jt) * 8;
      int n = n0 + (tid >> 5), j = tid & 31;
      const float* s1r = ws + WS_S1 + ((size_t)((b << 8) + n)) * 64;
      float acc = 0.f;
      #pragma unroll 4
      for (int kq = 0; kq < 64; ++kq) acc += s1r[kq] * sS[kq * 33 + j];
      out[262146 + ((size_t)((b << 8) + n)) * 32 + j] = acc;
    }
    if (blk == 255 && tid == 0) {
      float mc = 0.f, o = 0.f;
      #pragma unroll
      for (int b2 = 0; b2 < 16; ++b2) {
        mc += ws[WS_SCAL + b2] + ws[WS_SCAL + 32 + b2];
        o += ws[WS_SCAL + 16 + b2] + ws[WS_SCAL + 48 + b2];
      }
      out[262144] = -mc / 16.0f;
      out[262145] = o / 16.0f;
    }
  }
  gridBarrier(bcnt, bgen);

  // ---------------- Phase 7: conv3 -> out (blks 0..127)
  if (blk < 128) {
    int bt = blk, b = bt >> 3;
    float* sX = sm;            // 32*65 = 2080
    float* sA = sm + 2080;     // 32*33 = 1056
    float* sY = sm + 3136;     // 32*65 = 2080
    float* sWr = sm + 5216;    // 64*65 = 4160
    float* sWs = sm + 9376;    // 64*65 = 4160
    for (int idx = tid; idx < 2048; idx += 256)
      sX[(idx >> 6) * 65 + (idx & 63)] = ws[WS_X3 + (size_t)bt * 2048 + idx];
    for (int idx = tid; idx < 1024; idx += 256)
      sA[(idx >> 5) * 33 + (idx & 31)] = ws[WS_ADJ2 + (size_t)b * 1024 + idx];
    for (int idx = tid; idx < 4096; idx += 256) {
      int r = idx >> 6, c = idx & 63;
      sWr[r * 65 + c] = c3rW[idx];
      sWs[r * 65 + c] = c3sW[idx];
    }
    __syncthreads();
    int n = tid >> 3, h0 = (tid & 7) * 8;
    float acc[8];
    #pragma unroll
    for (int q = 0; q < 8; ++q) acc[q] = 0.f;
    for (int m = 0; m < 32; ++m) {
      float a = sA[n * 33 + m];
      #pragma unroll
      for (int q = 0; q < 8; ++q) acc[q] += a * sX[m * 65 + h0 + q];
    }
    #pragma unroll
    for (int q = 0; q < 8; ++q) sY[n * 65 + h0 + q] = acc[q];
    __syncthreads();
    #pragma unroll
    for (int q = 0; q < 8; ++q) acc[q] = c3rb[h0 + q];
    for (int m = 0; m < 64; ++m) {
      float y = sY[n * 65 + m], x = sX[n * 65 + m];
      #pragma unroll
      for (int q = 0; q < 8; ++q)
        acc[q] += y * sWr[m * 65 + h0 + q] + x * sWs[m * 65 + h0 + q];
    }
    #pragma unroll
    for (int q = 0; q < 8; ++q) out[(size_t)bt * 2048 + n * 64 + h0 + q] = acc[q];
  }
}

// ================================================================ launch
extern "C" void kernel_launch(void* const* d_in, const int* in_sizes, int n_in,
                              void* d_out, int out_size, void* d_ws, size_t ws_size,
                              hipStream_t stream) {
  (void)in_sizes; (void)n_in; (void)out_size; (void)ws_size;
  const float* pos = (const float*)d_in[0];
  const int* ei = (const int*)d_in[1];
  const float* ea = (const float*)d_in[2];
  const float* W1 = (const float*)d_in[4];
  const float* b1 = (const float*)d_in[5];
  const float* p1W = (const float*)d_in[6];
  const float* p1b = (const float*)d_in[7];
  const float* c2rW = (const float*)d_in[8];
  const float* c2rb = (const float*)d_in[9];
  const float* c2sW = (const float*)d_in[10];
  const float* p2W = (const float*)d_in[11];
  const float* p2b = (const float*)d_in[12];
  const float* c3rW = (const float*)d_in[13];
  const float* c3rb = (const float*)d_in[14];
  const float* c3sW = (const float*)d_in[15];
  float* ws = (float*)d_ws;
  float* out = (float*)d_out;

  // zero the grid-barrier state (counter+generation), capture-legal
  hipMemsetAsync((char*)d_ws + (size_t)WS_BAR * 4, 0, 8, stream);
  k_mega<<<dim3(NBLK), dim3(256), 0, stream>>>(
      pos, ei, ea, W1, b1, p1W, p1b, c2rW, c2rb, c2sW,
      p2W, p2b, c3rW, c3rb, c3sW, ws, out);
}

// Round 7
// 475.933 us; speedup vs baseline: 1.1141x; 1.1141x over previous
//
#include <hip/hip_runtime.h>
#include <cstdint>

// Single mega-kernel, plain launch: 256 blocks x 1024 threads (16 waves/CU =
// 4 waves/SIMD; VGPR capped at 128 by launch_bounds), hand-rolled grid
// barrier with agent-scope fences (R5-validated). Phases (redistributed for
// 1024 threads):
//  Z  zero WadjT/Adn/wsum
//  0  XW = pos@W1 (8 passes) + edge scatter (tid<256)
//  1  GCN+relu -> H + fused s1 (4 nodes concurrently x 4 iters)
//  2  AS1 (1 node/wave, single pass) + dflat
//  3  pool1 (blks 0..15, R1 1024-thr form) + x1 (blks 128..255)
//  4  conv2 (blks 0..127)
//  5  s2 + pool2 fused (blks 0..15)
//  6  x3 (0..127) + agg (128..255) + losses (blk 255)
//  7  conv3 -> out (0..127)

#define WS_WADJT 0
#define WS_ADN   1048576
#define WS_WSUM  2097152
#define WS_XW    2101248
#define WS_H     4198400
#define WS_S1    6295552
#define WS_TMP   6557696
#define WS_DFLAT 6819840
#define WS_ADJ1  6823936
#define WS_X1    6889472
#define WS_X2    7413760
#define WS_X3    7938048
#define WS_S2    8200192
#define WS_ADJ2  8232960
#define WS_SCAL  8249344
#define WS_BAR   8249408   // 2 ints: arrive counter, generation

#define NBLK 256

__device__ __forceinline__ void gridBarrier(int* cnt, int* gen) {
  __syncthreads();
  if (threadIdx.x == 0) {
    __threadfence();   // release
    int g = __hip_atomic_load(gen, __ATOMIC_RELAXED, __HIP_MEMORY_SCOPE_AGENT);
    int a = __hip_atomic_fetch_add(cnt, 1, __ATOMIC_ACQ_REL, __HIP_MEMORY_SCOPE_AGENT);
    if (a == NBLK - 1) {
      __hip_atomic_store(cnt, 0, __ATOMIC_RELAXED, __HIP_MEMORY_SCOPE_AGENT);
      __hip_atomic_fetch_add(gen, 1, __ATOMIC_ACQ_REL, __HIP_MEMORY_SCOPE_AGENT);
    } else {
      while (__hip_atomic_load(gen, __ATOMIC_RELAXED, __HIP_MEMORY_SCOPE_AGENT) == g) {}
    }
    __threadfence();   // acquire
  }
  __syncthreads();
}

// 1024-thread (16-wave) block reduction, red[16]
__device__ __forceinline__ float blockRedSum16(float v, float* red) {
  #pragma unroll
  for (int m = 32; m; m >>= 1) v += __shfl_xor(v, m);
  __syncthreads();
  if ((threadIdx.x & 63) == 0) red[threadIdx.x >> 6] = v;
  __syncthreads();
  float s = 0.f;
  #pragma unroll
  for (int i = 0; i < 16; ++i) s += red[i];
  __syncthreads();
  return s;
}

__global__ __launch_bounds__(1024) void k_mega(
    const float* __restrict__ pos, const int* __restrict__ ei, const float* __restrict__ ea,
    const float* __restrict__ W1, const float* __restrict__ b1,
    const float* __restrict__ p1W, const float* __restrict__ p1b,
    const float* __restrict__ c2rW, const float* __restrict__ c2rb, const float* __restrict__ c2sW,
    const float* __restrict__ p2W, const float* __restrict__ p2b,
    const float* __restrict__ c3rW, const float* __restrict__ c3rb, const float* __restrict__ c3sW,
    float* __restrict__ ws, float* __restrict__ out)
{
  int* bcnt = (int*)(ws + WS_BAR);
  int* bgen = (int*)(ws + WS_BAR) + 1;
  __shared__ float sm[20800];  // 83.2 KB (conv2 phase: 5 x 64x65)
  int tid = threadIdx.x, blk = blockIdx.x;
  int gtid = blk * 1024 + tid;

  // ---------------- Phase Z: zero WadjT + Adn + wsum (2101248 floats)
  {
    float4* p = (float4*)ws;
    for (int i = gtid; i < 525312; i += 262144) p[i] = make_float4(0.f, 0.f, 0.f, 0.f);
  }
  gridBarrier(bcnt, bgen);

  // ---------------- Phase 0: XW = pos @ W1 (32768 rows) ; edge scatter
  {
    for (int i = tid; i < 4096; i += 1024) sm[i] = W1[i];
    __syncthreads();
    int col = tid & 63;
    #pragma unroll
    for (int pass = 0; pass < 8; ++pass) {
      int row = blk * 128 + pass * 16 + (tid >> 6);
      const float* a = pos + (size_t)row * 64;
      float acc = 0.f;
      #pragma unroll 8
      for (int k = 0; k < 64; ++k) acc += a[k] * sm[k * 64 + col];
      ws[WS_XW + (size_t)row * 64 + col] = acc;
    }
    if (tid < 256) {
      int e = blk * 256 + tid;
      int s = ei[e], d = ei[65536 + e];
      int g = s >> 8, r = s & 255, c = d & 255;
      float w = ea[e];
      atomicAdd(&ws[WS_WADJT + (size_t)(((g << 8) + c) << 8) + r], w);
      atomicAdd(&ws[WS_ADN + (size_t)(((g << 8) + r) << 8) + c], 1.0f);
      atomicAdd(&ws[WS_WSUM + (g << 8) + c], w);
    }
  }
  gridBarrier(bcnt, bgen);

  // ---------------- Phase 1: GCN + relu -> H ; fused s1 (4 nodes x 4 iters)
  {
    float* sW = sm;                 // 4096 (p1W)
    float* dinvL = sm + 4096;       // 256
    float* pL = sm + 4352;          // 1024
    float* red4 = sm + 5376;        // 1024
    float* xm = sm + 6400;          // 256 (4 x 64)
    int* iL = (int*)(sm + 6656);    // 1024 ints
    int* wcnt = (int*)(sm + 7680);  // 16 ints
    int g = blk >> 4;
    for (int i = tid; i < 4096; i += 1024) sW[i] = p1W[i];
    if (tid < 256) dinvL[tid] = rsqrtf(ws[WS_WSUM + (g << 8) + tid] + 1.0f);
    __syncthreads();
    int ng = tid >> 8, ltid = tid & 255, lw = (tid >> 6) & 3, lane = tid & 63;
    float bb = b1[ltid & 63];
    for (int it = 0; it < 4; ++it) {
      int n = blk * 16 + it * 4 + ng;
      int cc = n & 255;
      float dn = dinvL[cc];
      float pv = ws[WS_WADJT + (size_t)n * 256 + ltid] * dinvL[ltid] * dn;
      if (ltid == cc) pv += dn * dn;
      bool act = (pv != 0.f);
      unsigned long long mask = __ballot(act);
      int wpos = (int)__popcll(mask & ((1ull << lane) - 1ull));
      if (lane == 0) wcnt[ng * 4 + lw] = (int)__popcll(mask);
      __syncthreads();
      int base = 0;
      #pragma unroll
      for (int i = 0; i < 4; ++i) base += (i < lw) ? wcnt[ng * 4 + i] : 0;
      int na = wcnt[ng * 4] + wcnt[ng * 4 + 1] + wcnt[ng * 4 + 2] + wcnt[ng * 4 + 3];
      if (act) { iL[ng * 256 + base + wpos] = ltid; pL[ng * 256 + base + wpos] = pv; }
      __syncthreads();
      const float* xg = ws + WS_XW + (size_t)g * 131072;
      float acc0 = 0.f, acc1 = 0.f;
      #pragma unroll 4
      for (int i = 0; i < na; ++i) {
        int r = iL[ng * 256 + i];
        float p = pL[ng * 256 + i];
        acc0 += p * xg[(size_t)r * 512 + ltid];
        acc1 += p * xg[(size_t)r * 512 + 256 + ltid];
      }
      acc0 = fmaxf(acc0 + bb, 0.f);
      acc1 = fmaxf(acc1 + bb, 0.f);
      float* hp = ws + WS_H + (size_t)n * 512;
      hp[ltid] = acc0;
      hp[256 + ltid] = acc1;
      red4[ng * 256 + lw * 64 + (ltid & 63)] = acc0 + acc1;
      __syncthreads();
      if (ltid < 64) {
        xm[ng * 64 + ltid] = 0.125f * (red4[ng * 256 + ltid] + red4[ng * 256 + 64 + ltid] +
                                       red4[ng * 256 + 128 + ltid] + red4[ng * 256 + 192 + ltid]);
        float a = p1b[ltid];
        #pragma unroll 4
        for (int kq = 0; kq < 64; ++kq) a += xm[ng * 64 + kq] * sW[kq * 64 + ltid];
        float v = tanhf(a);
        float mx = v;
        #pragma unroll
        for (int m = 32; m; m >>= 1) mx = fmaxf(mx, __shfl_xor(mx, m));
        float e = __expf(v - mx);
        float se = e;
        #pragma unroll
        for (int m = 32; m; m >>= 1) se += __shfl_xor(se, m);
        ws[WS_S1 + (size_t)n * 64 + ltid] = e / se;
      }
      __syncthreads();
    }
  }
  gridBarrier(bcnt, bgen);

  // ---------------- Phase 2: AS1 = Adn @ S1 (1 node per wave) + dflat
  {
    float* aL = sm;                 // 4096
    int* iLa = (int*)(sm + 4096);   // 4096 ints
    int w = tid >> 6, lane = tid & 63;
    int n = blk * 16 + w;
    int g = n >> 8;
    float4 av = *(const float4*)(ws + WS_ADN + (size_t)n * 256 + lane * 4);
    float rs = av.x + av.y + av.z + av.w;
    #pragma unroll
    for (int m = 32; m; m >>= 1) rs += __shfl_xor(rs, m);
    if (lane == 0) ws[WS_DFLAT + n] = rs;
    float avv[4] = {av.x, av.y, av.z, av.w};
    unsigned long long below = (1ull << lane) - 1ull;
    int base = 0;
    #pragma unroll
    for (int q = 0; q < 4; ++q) {
      bool act = (avv[q] != 0.f);
      unsigned long long mask = __ballot(act);
      if (act) {
        int p = base + (int)__popcll(mask & below);
        iLa[w * 256 + p] = lane * 4 + q;
        aL[w * 256 + p] = avv[q];
      }
      base += (int)__popcll(mask);
    }
    int na = base;
    float acc = 0.f;
    const float* S1g = ws + WS_S1 + ((size_t)g << 8) * 64;
    #pragma unroll 4
    for (int i = 0; i < na; ++i) {
      int m = iLa[w * 256 + i];
      float a = aL[w * 256 + i];
      acc += a * S1g[(size_t)m * 64 + lane];
    }
    ws[WS_TMP + (size_t)n * 64 + lane] = acc;
  }
  gridBarrier(bcnt, bgen);

  // ---------------- Phase 3: pool1 (blks 0..15, 1024 thr) + x1 (blks 128..255)
  if (blk < 16) {
    int b = blk;
    float* S1c = sm;          // 2048
    float* Tc = sm + 2048;    // 2048
    float* prs = sm + 4096;   // 64*17 = 1088
    float* diagL = sm + 5184; // 64
    float* dd = sm + 5248;    // 64
    float* red = sm + 5312;   // 16
    const float* Sb = ws + WS_S1 + (size_t)b * 16384;
    const float* Tb = ws + WS_TMP + (size_t)b * 16384;
    int k = tid >> 4, j0 = (tid & 15) * 4;
    float accA[4] = {0, 0, 0, 0}, accS[4] = {0, 0, 0, 0};
    for (int n0 = 0; n0 < 256; n0 += 32) {
      __syncthreads();
      S1c[tid] = Sb[n0 * 64 + tid];
      S1c[tid + 1024] = Sb[n0 * 64 + 1024 + tid];
      Tc[tid] = Tb[n0 * 64 + tid];
      Tc[tid + 1024] = Tb[n0 * 64 + 1024 + tid];
      __syncthreads();
      for (int i = 0; i < 32; ++i) {
        float sk = S1c[i * 64 + k];
        float4 tv = *(const float4*)(Tc + i * 64 + j0);
        float4 sv = *(const float4*)(S1c + i * 64 + j0);
        accA[0] += sk * tv.x; accA[1] += sk * tv.y; accA[2] += sk * tv.z; accA[3] += sk * tv.w;
        accS[0] += sk * sv.x; accS[1] += sk * sv.y; accS[2] += sk * sv.z; accS[3] += sk * sv.w;
      }
    }
    float num = 0.f, fro2 = 0.f, rsp = 0.f;
    #pragma unroll
    for (int q = 0; q < 4; ++q) { rsp += accA[q]; fro2 += accS[q] * accS[q]; }
    if (k >= j0 && k < j0 + 4) { num = accA[k - j0]; diagL[k] = accA[k - j0]; }
    prs[k * 17 + (tid & 15)] = rsp;
    __syncthreads();
    if (tid < 64) {
      float rs = 0.f;
      #pragma unroll
      for (int i = 0; i < 16; ++i) rs += prs[tid * 17 + i];
      dd[tid] = sqrtf(fmaxf(rs - diagL[tid], 0.f)) + 1e-15f;
    }
    float denp = 0.f;
    if (tid < 256) {
      const float* s = Sb + tid * 64;
      float qq = 0.f;
      for (int kk = 0; kk < 64; kk += 4) {
        float4 v = *(const float4*)(s + kk);
        qq += v.x * v.x + v.y * v.y + v.z * v.z + v.w * v.w;
      }
      denp = qq * ws[WS_DFLAT + (b << 8) + tid];
    }
    float numT = blockRedSum16(num, red);
    float denT = blockRedSum16(denp, red);
    float froT = sqrtf(blockRedSum16(fro2, red));
    float inv_fro = 1.f / froT;
    float osum = 0.f;
    #pragma unroll
    for (int q = 0; q < 4; ++q) {
      float v = accS[q] * inv_fro - ((j0 + q) == k ? 0.125f : 0.f);
      osum += v * v;
    }
    float orT = blockRedSum16(osum, red);
    float* adj = ws + WS_ADJ1 + (size_t)b * 4096;
    float dk = dd[k];
    #pragma unroll
    for (int q = 0; q < 4; ++q) {
      int j = j0 + q;
      adj[k * 64 + j] = (k == j) ? 0.f : accA[q] / (dk * dd[j]);
    }
    if (tid == 0) {
      ws[WS_SCAL + b] = numT / denT;
      ws[WS_SCAL + 16 + b] = sqrtf(orT);
    }
  } else if (blk >= 128) {
    // x1[b,t,k,h] = sum_n S1[b,n,k] h[b,n,t,h]
    int bt = blk - 128;
    int b = bt >> 3, t = bt & 7;
    int hc = tid & 63, kb = (tid >> 6) * 4;
    float* sS = sm;          // 2048
    float* sX = sm + 2048;   // 2048
    float acc[4] = {0, 0, 0, 0};
    for (int n0 = 0; n0 < 256; n0 += 32) {
      __syncthreads();
      for (int idx = tid; idx < 2048; idx += 1024) {
        int i = idx >> 6, c = idx & 63;
        sS[idx] = ws[WS_S1 + ((size_t)((b << 8) + n0 + i)) * 64 + c];
        sX[idx] = ws[WS_H + ((size_t)((b << 8) + n0 + i)) * 512 + t * 64 + c];
      }
      __syncthreads();
      for (int i = 0; i < 32; ++i) {
        float xv = sX[i * 64 + hc];
        #pragma unroll
        for (int q = 0; q < 4; ++q) acc[q] += sS[i * 64 + kb + q] * xv;
      }
    }
    #pragma unroll
    for (int q = 0; q < 4; ++q)
      ws[WS_X1 + ((size_t)bt * 64 + kb + q) * 64 + hc] = acc[q];
  }
  gridBarrier(bcnt, bgen);

  // ---------------- Phase 4: conv2 (blks 0..127)
  if (blk < 128) {
    int bt = blk;
    int b = bt >> 3;
    float* sA = sm;
    float* sX = sm + 4160;
    float* sY = sm + 8320;
    float* sWr = sm + 12480;
    float* sWs = sm + 16640;
    for (int idx = tid; idx < 4096; idx += 1024) {
      int r = idx >> 6, c = idx & 63;
      sA[r * 65 + c] = ws[WS_ADJ1 + (size_t)b * 4096 + idx];
      sX[r * 65 + c] = ws[WS_X1 + (size_t)bt * 4096 + idx];
      sWr[r * 65 + c] = c2rW[idx];
      sWs[r * 65 + c] = c2sW[idx];
    }
    __syncthreads();
    int n = tid >> 4, h0 = (tid & 15) * 4;
    float acc[4];
    #pragma unroll
    for (int q = 0; q < 4; ++q) acc[q] = 0.f;
    for (int m = 0; m < 64; ++m) {
      float a = sA[n * 65 + m];
      #pragma unroll
      for (int q = 0; q < 4; ++q) acc[q] += a * sX[m * 65 + h0 + q];
    }
    #pragma unroll
    for (int q = 0; q < 4; ++q) sY[n * 65 + h0 + q] = acc[q];
    __syncthreads();
    #pragma unroll
    for (int q = 0; q < 4; ++q) acc[q] = c2rb[h0 + q];
    for (int m = 0; m < 64; ++m) {
      float y = sY[n * 65 + m], x = sX[n * 65 + m];
      #pragma unroll
      for (int q = 0; q < 4; ++q)
        acc[q] += y * sWr[m * 65 + h0 + q] + x * sWs[m * 65 + h0 + q];
    }
    #pragma unroll
    for (int q = 0; q < 4; ++q)
      ws[WS_X2 + (size_t)bt * 4096 + n * 64 + h0 + q] = fmaxf(acc[q], 0.f);
  }
  gridBarrier(bcnt, bgen);

  // ---------------- Phase 5: s2 (in LDS) + pool2 fused (blks 0..15)
  if (blk < 16) {
    int b = blk;
    float* xmL = sm;            // 4096
    float* sS2 = sm + 4096;     // 64*33 = 2112
    float* sA2 = sm + 6208;     // 64*65 = 4160
    float* sT  = sm + 10368;    // 64*33 = 2112
    float* oaL = sm + 12480;    // 32*33 = 1056
    float* ssL = sm + 13536;    // 32*33 = 1056
    float* sdf = sm + 14592;    // 64
    float* ddL = sm + 14656;    // 32
    float* red = sm + 14688;    // 16
    float* sp2W = sm + 14704;   // 2048
    for (int idx = tid; idx < 4096; idx += 1024)
      sA2[(idx >> 6) * 65 + (idx & 63)] = ws[WS_ADJ1 + (size_t)b * 4096 + idx];
    for (int idx = tid; idx < 2048; idx += 1024) sp2W[idx] = p2W[idx];
    for (int idx = tid; idx < 4096; idx += 1024) {
      int n = idx >> 6, f = idx & 63;
      float s = 0.f;
      #pragma unroll
      for (int t = 0; t < 8; ++t)
        s += ws[WS_X2 + ((size_t)(b * 8 + t) * 64 + n) * 64 + f];
      xmL[idx] = s * 0.125f;
    }
    __syncthreads();
    // S2: node n = tid>>4 (0..63), 2 outputs each; softmax over 16-lane groups
    {
      int n = tid >> 4, j0 = (tid & 15) * 2;
      float a0 = p2b[j0], a1 = p2b[j0 + 1];
      for (int kq = 0; kq < 64; ++kq) {
        float v = xmL[n * 64 + kq];
        a0 += v * sp2W[kq * 32 + j0];
        a1 += v * sp2W[kq * 32 + j0 + 1];
      }
      float v0 = tanhf(a0), v1 = tanhf(a1);
      float mx = fmaxf(v0, v1);
      #pragma unroll
      for (int off = 8; off; off >>= 1) mx = fmaxf(mx, __shfl_xor(mx, off));
      float e0 = __expf(v0 - mx), e1 = __expf(v1 - mx);
      float se = e0 + e1;
      #pragma unroll
      for (int off = 8; off; off >>= 1) se += __shfl_xor(se, off);
      float inv = 1.f / se;
      e0 *= inv; e1 *= inv;
      sS2[n * 33 + j0] = e0;
      sS2[n * 33 + j0 + 1] = e1;
      ws[WS_S2 + (size_t)(b * 64 + n) * 32 + j0] = e0;
      ws[WS_S2 + (size_t)(b * 64 + n) * 32 + j0 + 1] = e1;
    }
    __syncthreads();
    if (tid < 64) {
      float s = 0.f;
      for (int m = 0; m < 64; ++m) s += sA2[tid * 65 + m];
      sdf[tid] = s;
    }
    // sT = adj1 @ S2 : 2 outputs/thread
    {
      int n2 = tid >> 4, j0 = (tid & 15) * 2;
      float t0 = 0.f, t1 = 0.f;
      for (int m = 0; m < 64; ++m) {
        float a = sA2[n2 * 65 + m];
        t0 += a * sS2[m * 33 + j0];
        t1 += a * sS2[m * 33 + j0 + 1];
      }
      sT[n2 * 33 + j0] = t0;
      sT[n2 * 33 + j0 + 1] = t1;
    }
    float accD = 0.f;
    if (tid < 64) {
      float t = 0.f;
      for (int q = 0; q < 32; ++q) { float v = sS2[tid * 33 + q]; t += v * v; }
      accD = t * sdf[tid];
    }
    __syncthreads();
    // oa/ss: 1 output/thread (32x32)
    int k5 = tid >> 5, j5 = tid & 31;
    float accA = 0.f, accS = 0.f;
    for (int n3 = 0; n3 < 64; ++n3) {
      float sk = sS2[n3 * 33 + k5];
      accA += sk * sT[n3 * 33 + j5];
      accS += sk * sS2[n3 * 33 + j5];
    }
    oaL[k5 * 33 + j5] = accA;
    ssL[k5 * 33 + j5] = accS;
    float fro2p = accS * accS;
    __syncthreads();
    float num = 0.f, trs = 0.f;
    if (tid < 32) {
      num = oaL[tid * 33 + tid];
      trs = ssL[tid * 33 + tid];
      float rs = 0.f;
      for (int j = 0; j < 32; ++j) rs += oaL[tid * 33 + j];
      ddL[tid] = sqrtf(fmaxf(rs - num, 0.f)) + 1e-15f;
    }
    float numT = blockRedSum16(num, red);
    float denT = blockRedSum16(accD, red);
    float froT = sqrtf(blockRedSum16(fro2p, red));
    float trT = blockRedSum16(trs, red);
    {
      float dk = ddL[k5];
      float* a2 = ws + WS_ADJ2 + (size_t)b * 1024;
      a2[k5 * 32 + j5] = (k5 == j5) ? 0.f : oaL[k5 * 33 + j5] / (dk * ddL[j5]);
    }
    if (tid == 0) {
      ws[WS_SCAL + 32 + b] = numT / denT;
      ws[WS_SCAL + 48 + b] = sqrtf(fmaxf(2.f - 2.f * trT / (5.656854249f * froT), 0.f));
    }
  }
  gridBarrier(bcnt, bgen);

  // ---------------- Phase 6: x3 (blks 0..127) + agg (blks 128..255) + losses
  if (blk < 128) {
    int bt = blk, b = bt >> 3;
    float* sX = sm;           // 64*65
    float* sS = sm + 4160;    // 64*33
    for (int idx = tid; idx < 4096; idx += 1024)
      sX[(idx >> 6) * 65 + (idx & 63)] = ws[WS_X2 + (size_t)bt * 4096 + idx];
    for (int idx = tid; idx < 2048; idx += 1024)
      sS[(idx >> 5) * 33 + (idx & 31)] = ws[WS_S2 + (size_t)b * 2048 + idx];
    __syncthreads();
    int k = tid >> 5, h0 = (tid & 31) * 2;
    float a0 = 0.f, a1 = 0.f;
    for (int n = 0; n < 64; ++n) {
      float sv = sS[n * 33 + k];
      a0 += sv * sX[n * 65 + h0];
      a1 += sv * sX[n * 65 + h0 + 1];
    }
    ws[WS_X3 + (size_t)bt * 2048 + k * 64 + h0] = a0;
    ws[WS_X3 + (size_t)bt * 2048 + k * 64 + h0 + 1] = a1;
  } else {
    int rb = blk - 128;
    int b = rb >> 3, sub = rb & 7;
    float* sS = sm;  // 64*33
    for (int idx = tid; idx < 2048; idx += 1024)
      sS[(idx >> 5) * 33 + (idx & 31)] = ws[WS_S2 + (size_t)b * 2048 + idx];
    __syncthreads();
    int n = sub * 32 + (tid >> 5), j = tid & 31;
    const float* s1r = ws + WS_S1 + ((size_t)((b << 8) + n)) * 64;
    float acc = 0.f;
    #pragma unroll 4
    for (int kq = 0; kq < 64; ++kq) acc += s1r[kq] * sS[kq * 33 + j];
    out[262146 + ((size_t)((b << 8) + n)) * 32 + j] = acc;
    if (blk == 255 && tid == 0) {
      float mc = 0.f, o = 0.f;
      #pragma unroll
      for (int b2 = 0; b2 < 16; ++b2) {
        mc += ws[WS_SCAL + b2] + ws[WS_SCAL + 32 + b2];
        o += ws[WS_SCAL + 16 + b2] + ws[WS_SCAL + 48 + b2];
      }
      out[262144] = -mc / 16.0f;
      out[262145] = o / 16.0f;
    }
  }
  gridBarrier(bcnt, bgen);

  // ---------------- Phase 7: conv3 -> out (blks 0..127)
  if (blk < 128) {
    int bt = blk, b = bt >> 3;
    float* sX = sm;            // 32*65 = 2080
    float* sA = sm + 2080;     // 32*33 = 1056
    float* sY = sm + 3136;     // 32*65 = 2080
    float* sWr = sm + 5216;    // 64*65 = 4160
    float* sWs = sm + 9376;    // 64*65 = 4160
    for (int idx = tid; idx < 2048; idx += 1024)
      sX[(idx >> 6) * 65 + (idx & 63)] = ws[WS_X3 + (size_t)bt * 2048 + idx];
    if (tid < 1024) {
      int idx = tid;
      sA[(idx >> 5) * 33 + (idx & 31)] = ws[WS_ADJ2 + (size_t)b * 1024 + idx];
    }
    for (int idx = tid; idx < 4096; idx += 1024) {
      int r = idx >> 6, c = idx & 63;
      sWr[r * 65 + c] = c3rW[idx];
      sWs[r * 65 + c] = c3sW[idx];
    }
    __syncthreads();
    int n = tid >> 5, h0 = (tid & 31) * 2;
    float a0 = 0.f, a1 = 0.f;
    for (int m = 0; m < 32; ++m) {
      float a = sA[n * 33 + m];
      a0 += a * sX[m * 65 + h0];
      a1 += a * sX[m * 65 + h0 + 1];
    }
    sY[n * 65 + h0] = a0;
    sY[n * 65 + h0 + 1] = a1;
    __syncthreads();
    a0 = c3rb[h0]; a1 = c3rb[h0 + 1];
    for (int m = 0; m < 64; ++m) {
      float y = sY[n * 65 + m], x = sX[n * 65 + m];
      a0 += y * sWr[m * 65 + h0] + x * sWs[m * 65 + h0];
      a1 += y * sWr[m * 65 + h0 + 1] + x * sWs[m * 65 + h0 + 1];
    }
    out[(size_t)bt * 2048 + n * 64 + h0] = a0;
    out[(size_t)bt * 2048 + n * 64 + h0 + 1] = a1;
  }
}

// ================================================================ launch
extern "C" void kernel_launch(void* const* d_in, const int* in_sizes, int n_in,
                              void* d_out, int out_size, void* d_ws, size_t ws_size,
                              hipStream_t stream) {
  (void)in_sizes; (void)n_in; (void)out_size; (void)ws_size;
  const float* pos = (const float*)d_in[0];
  const int* ei = (const int*)d_in[1];
  const float* ea = (const float*)d_in[2];
  const float* W1 = (const float*)d_in[4];
  const float* b1 = (const float*)d_in[5];
  const float* p1W = (const float*)d_in[6];
  const float* p1b = (const float*)d_in[7];
  const float* c2rW = (const float*)d_in[8];
  const float* c2rb = (const float*)d_in[9];
  const float* c2sW = (const float*)d_in[10];
  const float* p2W = (const float*)d_in[11];
  const float* p2b = (const float*)d_in[12];
  const float* c3rW = (const float*)d_in[13];
  const float* c3rb = (const float*)d_in[14];
  const float* c3sW = (const float*)d_in[15];
  float* ws = (float*)d_ws;
  float* out = (float*)d_out;

  // zero the grid-barrier state (counter+generation), capture-legal
  hipMemsetAsync((char*)d_ws + (size_t)WS_BAR * 4, 0, 8, stream);
  k_mega<<<dim3(NBLK), dim3(1024), 0, stream>>>(
      pos, ei, ea, W1, b1, p1W, p1b, c2rW, c2rb, c2sW,
      p2W, p2b, c3rW, c3rb, c3sW, ws, out);
}

// Round 11
// 359.720 us; speedup vs baseline: 1.4740x; 1.3231x over previous
//
#include <hip/hip_runtime.h>
#include <cstdint>

// Mega-kernel v3.1: 256 blocks x 1024 threads, cheap hierarchical barriers
// WITH explicit threadfences (R7-validated visibility pattern).
//  - zeroing via hipMemsetAsync (no in-kernel phase Z)
//  - 5 global barriers (16-leaf hierarchy + s_sleep backoff) + 1 per-graph
//    16-block barrier (1->2)
//  - x3+conv3 merged (x3 stays in LDS; X3 never hits global)
// Phases:
//  0  XW = pos@W1 (8 passes) + edge scatter (tid<256)         [GLOBAL]
//  1  GCN+relu -> H + fused s1 (4 nodes x 4 iters)            [GRAPH-LOCAL]
//  2  AS1 (1 node/wave) + dflat                               [GLOBAL]
//  3  pool1 (blks 0..15) + x1 (blks 128..255)                 [GLOBAL]
//  4  conv2 (blks 0..127)                                     [GLOBAL]
//  5  s2 + pool2 fused (blks 0..15)                           [GLOBAL]
//  67 x3+conv3 in-LDS (blks 0..127) + agg (128..255) + losses

#define WS_WADJT 0
#define WS_ADN   1048576
#define WS_WSUM  2097152
#define WS_XW    2101248
#define WS_H     4198400
#define WS_S1    6295552
#define WS_TMP   6557696
#define WS_DFLAT 6819840
#define WS_ADJ1  6823936
#define WS_X1    6889472
#define WS_X2    7413760
#define WS_X3    7938048
#define WS_S2    8200192
#define WS_ADJ2  8232960
#define WS_SCAL  8249344
#define WS_BAR   8249408   // int region: see layout below

#define NBLK 256

// Barrier state layout (ints, base = ws + WS_BAR):
//  [g*32]            g=0..15  global leaf counters (128B apart)
//  [512]                      global root counter
//  [544]                      global generation
//  [576 + g*32]      g=0..15  per-graph local counter
//  [576 + g*32 + 16] g=0..15  per-graph local generation
// Total 1088 ints; zeroed by host memset each launch.

__device__ __forceinline__ void gridBarrier(int* bar) {
  __syncthreads();
  if (threadIdx.x == 0) {
    __threadfence();   // release: flush this block's stores (cross-XCD)
    int grp = blockIdx.x >> 4;
    int* leaf = bar + grp * 32;
    int* root = bar + 512;
    int* gen  = bar + 544;
    int g = __hip_atomic_load(gen, __ATOMIC_RELAXED, __HIP_MEMORY_SCOPE_AGENT);
    int a = __hip_atomic_fetch_add(leaf, 1, __ATOMIC_ACQ_REL, __HIP_MEMORY_SCOPE_AGENT);
    if (a == 15) {
      int r = __hip_atomic_fetch_add(root, 1, __ATOMIC_ACQ_REL, __HIP_MEMORY_SCOPE_AGENT);
      if (r == 15) {
        #pragma unroll
        for (int i = 0; i < 16; ++i)
          __hip_atomic_store(bar + i * 32, 0, __ATOMIC_RELAXED, __HIP_MEMORY_SCOPE_AGENT);
        __hip_atomic_store(root, 0, __ATOMIC_RELAXED, __HIP_MEMORY_SCOPE_AGENT);
        __hip_atomic_fetch_add(gen, 1, __ATOMIC_RELEASE, __HIP_MEMORY_SCOPE_AGENT);
      }
    }
    while (__hip_atomic_load(gen, __ATOMIC_RELAXED, __HIP_MEMORY_SCOPE_AGENT) == g)
      __builtin_amdgcn_s_sleep(2);
    __threadfence();   // acquire: invalidate stale lines before phase reads
  }
  __syncthreads();
}

// 16-block barrier among the blocks of one graph group (blk>>4).
// Group blocks may span XCDs (round-robin dispatch) -> same fence pattern.
__device__ __forceinline__ void graphBarrier(int* bar) {
  __syncthreads();
  if (threadIdx.x == 0) {
    __threadfence();
    int grp = blockIdx.x >> 4;
    int* cnt = bar + 576 + grp * 32;
    int* gen = bar + 576 + grp * 32 + 16;
    int g = __hip_atomic_load(gen, __ATOMIC_RELAXED, __HIP_MEMORY_SCOPE_AGENT);
    int a = __hip_atomic_fetch_add(cnt, 1, __ATOMIC_ACQ_REL, __HIP_MEMORY_SCOPE_AGENT);
    if (a == 15) {
      __hip_atomic_store(cnt, 0, __ATOMIC_RELAXED, __HIP_MEMORY_SCOPE_AGENT);
      __hip_atomic_fetch_add(gen, 1, __ATOMIC_RELEASE, __HIP_MEMORY_SCOPE_AGENT);
    }
    while (__hip_atomic_load(gen, __ATOMIC_RELAXED, __HIP_MEMORY_SCOPE_AGENT) == g)
      __builtin_amdgcn_s_sleep(1);
    __threadfence();
  }
  __syncthreads();
}

// 1024-thread (16-wave) block reduction, red[16]
__device__ __forceinline__ float blockRedSum16(float v, float* red) {
  #pragma unroll
  for (int m = 32; m; m >>= 1) v += __shfl_xor(v, m);
  __syncthreads();
  if ((threadIdx.x & 63) == 0) red[threadIdx.x >> 6] = v;
  __syncthreads();
  float s = 0.f;
  #pragma unroll
  for (int i = 0; i < 16; ++i) s += red[i];
  __syncthreads();
  return s;
}

__global__ __launch_bounds__(1024) void k_mega(
    const float* __restrict__ pos, const int* __restrict__ ei, const float* __restrict__ ea,
    const float* __restrict__ W1, const float* __restrict__ b1,
    const float* __restrict__ p1W, const float* __restrict__ p1b,
    const float* __restrict__ c2rW, const float* __restrict__ c2rb, const float* __restrict__ c2sW,
    const float* __restrict__ p2W, const float* __restrict__ p2b,
    const float* __restrict__ c3rW, const float* __restrict__ c3rb, const float* __restrict__ c3sW,
    float* __restrict__ ws, float* __restrict__ out)
{
  int* bar = (int*)(ws + WS_BAR);
  __shared__ float sm[20800];  // 83.2 KB (conv2 phase: 5 x 64x65)
  int tid = threadIdx.x, blk = blockIdx.x;

  // ---------------- Phase 0: XW = pos @ W1 (32768 rows) ; edge scatter
  {
    for (int i = tid; i < 4096; i += 1024) sm[i] = W1[i];
    __syncthreads();
    int col = tid & 63;
    #pragma unroll
    for (int pass = 0; pass < 8; ++pass) {
      int row = blk * 128 + pass * 16 + (tid >> 6);
      const float* a = pos + (size_t)row * 64;
      float acc = 0.f;
      #pragma unroll 8
      for (int k = 0; k < 64; ++k) acc += a[k] * sm[k * 64 + col];
      ws[WS_XW + (size_t)row * 64 + col] = acc;
    }
    if (tid < 256) {
      int e = blk * 256 + tid;
      int s = ei[e], d = ei[65536 + e];
      int g = s >> 8, r = s & 255, c = d & 255;
      float w = ea[e];
      atomicAdd(&ws[WS_WADJT + (size_t)(((g << 8) + c) << 8) + r], w);
      atomicAdd(&ws[WS_ADN + (size_t)(((g << 8) + r) << 8) + c], 1.0f);
      atomicAdd(&ws[WS_WSUM + (g << 8) + c], w);
    }
  }
  gridBarrier(bar);

  // ---------------- Phase 1: GCN + relu -> H ; fused s1 (4 nodes x 4 iters)
  {
    float* sW = sm;                 // 4096 (p1W)
    float* dinvL = sm + 4096;       // 256
    float* pL = sm + 4352;          // 1024
    float* red4 = sm + 5376;        // 1024
    float* xm = sm + 6400;          // 256 (4 x 64)
    int* iL = (int*)(sm + 6656);    // 1024 ints
    int* wcnt = (int*)(sm + 7680);  // 16 ints
    int g = blk >> 4;
    for (int i = tid; i < 4096; i += 1024) sW[i] = p1W[i];
    if (tid < 256) dinvL[tid] = rsqrtf(ws[WS_WSUM + (g << 8) + tid] + 1.0f);
    __syncthreads();
    int ng = tid >> 8, ltid = tid & 255, lw = (tid >> 6) & 3, lane = tid & 63;
    float bb = b1[ltid & 63];
    for (int it = 0; it < 4; ++it) {
      int n = blk * 16 + it * 4 + ng;
      int cc = n & 255;
      float dn = dinvL[cc];
      float pv = ws[WS_WADJT + (size_t)n * 256 + ltid] * dinvL[ltid] * dn;
      if (ltid == cc) pv += dn * dn;
      bool act = (pv != 0.f);
      unsigned long long mask = __ballot(act);
      int wpos = (int)__popcll(mask & ((1ull << lane) - 1ull));
      if (lane == 0) wcnt[ng * 4 + lw] = (int)__popcll(mask);
      __syncthreads();
      int base = 0;
      #pragma unroll
      for (int i = 0; i < 4; ++i) base += (i < lw) ? wcnt[ng * 4 + i] : 0;
      int na = wcnt[ng * 4] + wcnt[ng * 4 + 1] + wcnt[ng * 4 + 2] + wcnt[ng * 4 + 3];
      if (act) { iL[ng * 256 + base + wpos] = ltid; pL[ng * 256 + base + wpos] = pv; }
      __syncthreads();
      const float* xg = ws + WS_XW + (size_t)g * 131072;
      float acc0 = 0.f, acc1 = 0.f;
      #pragma unroll 4
      for (int i = 0; i < na; ++i) {
        int r = iL[ng * 256 + i];
        float p = pL[ng * 256 + i];
        acc0 += p * xg[(size_t)r * 512 + ltid];
        acc1 += p * xg[(size_t)r * 512 + 256 + ltid];
      }
      acc0 = fmaxf(acc0 + bb, 0.f);
      acc1 = fmaxf(acc1 + bb, 0.f);
      float* hp = ws + WS_H + (size_t)n * 512;
      hp[ltid] = acc0;
      hp[256 + ltid] = acc1;
      red4[ng * 256 + lw * 64 + (ltid & 63)] = acc0 + acc1;
      __syncthreads();
      if (ltid < 64) {
        xm[ng * 64 + ltid] = 0.125f * (red4[ng * 256 + ltid] + red4[ng * 256 + 64 + ltid] +
                                       red4[ng * 256 + 128 + ltid] + red4[ng * 256 + 192 + ltid]);
        float a = p1b[ltid];
        #pragma unroll 4
        for (int kq = 0; kq < 64; ++kq) a += xm[ng * 64 + kq] * sW[kq * 64 + ltid];
        float v = tanhf(a);
        float mx = v;
        #pragma unroll
        for (int m = 32; m; m >>= 1) mx = fmaxf(mx, __shfl_xor(mx, m));
        float e = __expf(v - mx);
        float se = e;
        #pragma unroll
        for (int m = 32; m; m >>= 1) se += __shfl_xor(se, m);
        ws[WS_S1 + (size_t)n * 64 + ltid] = e / se;
      }
      __syncthreads();
    }
  }
  graphBarrier(bar);   // S1 of graph g produced+consumed within block group g

  // ---------------- Phase 2: AS1 = Adn @ S1 (1 node per wave) + dflat
  {
    float* aL = sm;                 // 4096
    int* iLa = (int*)(sm + 4096);   // 4096 ints
    int w = tid >> 6, lane = tid & 63;
    int n = blk * 16 + w;
    int g = n >> 8;
    float4 av = *(const float4*)(ws + WS_ADN + (size_t)n * 256 + lane * 4);
    float rs = av.x + av.y + av.z + av.w;
    #pragma unroll
    for (int m = 32; m; m >>= 1) rs += __shfl_xor(rs, m);
    if (lane == 0) ws[WS_DFLAT + n] = rs;
    float avv[4] = {av.x, av.y, av.z, av.w};
    unsigned long long below = (1ull << lane) - 1ull;
    int base = 0;
    #pragma unroll
    for (int q = 0; q < 4; ++q) {
      bool act = (avv[q] != 0.f);
      unsigned long long mask = __ballot(act);
      if (act) {
        int p = base + (int)__popcll(mask & below);
        iLa[w * 256 + p] = lane * 4 + q;
        aL[w * 256 + p] = avv[q];
      }
      base += (int)__popcll(mask);
    }
    int na = base;
    float acc = 0.f;
    const float* S1g = ws + WS_S1 + ((size_t)g << 8) * 64;
    #pragma unroll 4
    for (int i = 0; i < na; ++i) {
      int m = iLa[w * 256 + i];
      float a = aL[w * 256 + i];
      acc += a * S1g[(size_t)m * 64 + lane];
    }
    ws[WS_TMP + (size_t)n * 64 + lane] = acc;
  }
  gridBarrier(bar);

  // ---------------- Phase 3: pool1 (blks 0..15, 1024 thr) + x1 (blks 128..255)
  if (blk < 16) {
    int b = blk;
    float* S1c = sm;          // 2048
    float* Tc = sm + 2048;    // 2048
    float* prs = sm + 4096;   // 64*17 = 1088
    float* diagL = sm + 5184; // 64
    float* dd = sm + 5248;    // 64
    float* red = sm + 5312;   // 16
    const float* Sb = ws + WS_S1 + (size_t)b * 16384;
    const float* Tb = ws + WS_TMP + (size_t)b * 16384;
    int k = tid >> 4, j0 = (tid & 15) * 4;
    float accA[4] = {0, 0, 0, 0}, accS[4] = {0, 0, 0, 0};
    for (int n0 = 0; n0 < 256; n0 += 32) {
      __syncthreads();
      S1c[tid] = Sb[n0 * 64 + tid];
      S1c[tid + 1024] = Sb[n0 * 64 + 1024 + tid];
      Tc[tid] = Tb[n0 * 64 + tid];
      Tc[tid + 1024] = Tb[n0 * 64 + 1024 + tid];
      __syncthreads();
      for (int i = 0; i < 32; ++i) {
        float sk = S1c[i * 64 + k];
        float4 tv = *(const float4*)(Tc + i * 64 + j0);
        float4 sv = *(const float4*)(S1c + i * 64 + j0);
        accA[0] += sk * tv.x; accA[1] += sk * tv.y; accA[2] += sk * tv.z; accA[3] += sk * tv.w;
        accS[0] += sk * sv.x; accS[1] += sk * sv.y; accS[2] += sk * sv.z; accS[3] += sk * sv.w;
      }
    }
    float num = 0.f, fro2 = 0.f, rsp = 0.f;
    #pragma unroll
    for (int q = 0; q < 4; ++q) { rsp += accA[q]; fro2 += accS[q] * accS[q]; }
    if (k >= j0 && k < j0 + 4) { num = accA[k - j0]; diagL[k] = accA[k - j0]; }
    prs[k * 17 + (tid & 15)] = rsp;
    __syncthreads();
    if (tid < 64) {
      float rs = 0.f;
      #pragma unroll
      for (int i = 0; i < 16; ++i) rs += prs[tid * 17 + i];
      dd[tid] = sqrtf(fmaxf(rs - diagL[tid], 0.f)) + 1e-15f;
    }
    float denp = 0.f;
    if (tid < 256) {
      const float* s = Sb + tid * 64;
      float qq = 0.f;
      for (int kk = 0; kk < 64; kk += 4) {
        float4 v = *(const float4*)(s + kk);
        qq += v.x * v.x + v.y * v.y + v.z * v.z + v.w * v.w;
      }
      denp = qq * ws[WS_DFLAT + (b << 8) + tid];
    }
    float numT = blockRedSum16(num, red);
    float denT = blockRedSum16(denp, red);
    float froT = sqrtf(blockRedSum16(fro2, red));
    float inv_fro = 1.f / froT;
    float osum = 0.f;
    #pragma unroll
    for (int q = 0; q < 4; ++q) {
      float v = accS[q] * inv_fro - ((j0 + q) == k ? 0.125f : 0.f);
      osum += v * v;
    }
    float orT = blockRedSum16(osum, red);
    float* adj = ws + WS_ADJ1 + (size_t)b * 4096;
    float dk = dd[k];
    #pragma unroll
    for (int q = 0; q < 4; ++q) {
      int j = j0 + q;
      adj[k * 64 + j] = (k == j) ? 0.f : accA[q] / (dk * dd[j]);
    }
    if (tid == 0) {
      ws[WS_SCAL + b] = numT / denT;
      ws[WS_SCAL + 16 + b] = sqrtf(orT);
    }
  } else if (blk >= 128) {
    // x1[b,t,k,h] = sum_n S1[b,n,k] h[b,n,t,h]
    int bt = blk - 128;
    int b = bt >> 3, t = bt & 7;
    int hc = tid & 63, kb = (tid >> 6) * 4;
    float* sS = sm;          // 2048
    float* sX = sm + 2048;   // 2048
    float acc[4] = {0, 0, 0, 0};
    for (int n0 = 0; n0 < 256; n0 += 32) {
      __syncthreads();
      for (int idx = tid; idx < 2048; idx += 1024) {
        int i = idx >> 6, c = idx & 63;
        sS[idx] = ws[WS_S1 + ((size_t)((b << 8) + n0 + i)) * 64 + c];
        sX[idx] = ws[WS_H + ((size_t)((b << 8) + n0 + i)) * 512 + t * 64 + c];
      }
      __syncthreads();
      for (int i = 0; i < 32; ++i) {
        float xv = sX[i * 64 + hc];
        #pragma unroll
        for (int q = 0; q < 4; ++q) acc[q] += sS[i * 64 + kb + q] * xv;
      }
    }
    #pragma unroll
    for (int q = 0; q < 4; ++q)
      ws[WS_X1 + ((size_t)bt * 64 + kb + q) * 64 + hc] = acc[q];
  }
  gridBarrier(bar);

  // ---------------- Phase 4: conv2 (blks 0..127)
  if (blk < 128) {
    int bt = blk;
    int b = bt >> 3;
    float* sA = sm;
    float* sX = sm + 4160;
    float* sY = sm + 8320;
    float* sWr = sm + 12480;
    float* sWs = sm + 16640;
    for (int idx = tid; idx < 4096; idx += 1024) {
      int r = idx >> 6, c = idx & 63;
      sA[r * 65 + c] = ws[WS_ADJ1 + (size_t)b * 4096 + idx];
      sX[r * 65 + c] = ws[WS_X1 + (size_t)bt * 4096 + idx];
      sWr[r * 65 + c] = c2rW[idx];
      sWs[r * 65 + c] = c2sW[idx];
    }
    __syncthreads();
    int n = tid >> 4, h0 = (tid & 15) * 4;
    float acc[4];
    #pragma unroll
    for (int q = 0; q < 4; ++q) acc[q] = 0.f;
    for (int m = 0; m < 64; ++m) {
      float a = sA[n * 65 + m];
      #pragma unroll
      for (int q = 0; q < 4; ++q) acc[q] += a * sX[m * 65 + h0 + q];
    }
    #pragma unroll
    for (int q = 0; q < 4; ++q) sY[n * 65 + h0 + q] = acc[q];
    __syncthreads();
    #pragma unroll
    for (int q = 0; q < 4; ++q) acc[q] = c2rb[h0 + q];
    for (int m = 0; m < 64; ++m) {
      float y = sY[n * 65 + m], x = sX[n * 65 + m];
      #pragma unroll
      for (int q = 0; q < 4; ++q)
        acc[q] += y * sWr[m * 65 + h0 + q] + x * sWs[m * 65 + h0 + q];
    }
    #pragma unroll
    for (int q = 0; q < 4; ++q)
      ws[WS_X2 + (size_t)bt * 4096 + n * 64 + h0 + q] = fmaxf(acc[q], 0.f);
  }
  gridBarrier(bar);

  // ---------------- Phase 5: s2 (in LDS) + pool2 fused (blks 0..15)
  if (blk < 16) {
    int b = blk;
    float* xmL = sm;            // 4096
    float* sS2 = sm + 4096;     // 64*33 = 2112
    float* sA2 = sm + 6208;     // 64*65 = 4160
    float* sT  = sm + 10368;    // 64*33 = 2112
    float* oaL = sm + 12480;    // 32*33 = 1056
    float* ssL = sm + 13536;    // 32*33 = 1056
    float* sdf = sm + 14592;    // 64
    float* ddL = sm + 14656;    // 32
    float* red = sm + 14688;    // 16
    float* sp2W = sm + 14704;   // 2048
    for (int idx = tid; idx < 4096; idx += 1024)
      sA2[(idx >> 6) * 65 + (idx & 63)] = ws[WS_ADJ1 + (size_t)b * 4096 + idx];
    for (int idx = tid; idx < 2048; idx += 1024) sp2W[idx] = p2W[idx];
    for (int idx = tid; idx < 4096; idx += 1024) {
      int n = idx >> 6, f = idx & 63;
      float s = 0.f;
      #pragma unroll
      for (int t = 0; t < 8; ++t)
        s += ws[WS_X2 + ((size_t)(b * 8 + t) * 64 + n) * 64 + f];
      xmL[idx] = s * 0.125f;
    }
    __syncthreads();
    // S2: node n = tid>>4 (0..63), 2 outputs each; softmax over 16-lane groups
    {
      int n = tid >> 4, j0 = (tid & 15) * 2;
      float a0 = p2b[j0], a1 = p2b[j0 + 1];
      for (int kq = 0; kq < 64; ++kq) {
        float v = xmL[n * 64 + kq];
        a0 += v * sp2W[kq * 32 + j0];
        a1 += v * sp2W[kq * 32 + j0 + 1];
      }
      float v0 = tanhf(a0), v1 = tanhf(a1);
      float mx = fmaxf(v0, v1);
      #pragma unroll
      for (int off = 8; off; off >>= 1) mx = fmaxf(mx, __shfl_xor(mx, off));
      float e0 = __expf(v0 - mx), e1 = __expf(v1 - mx);
      float se = e0 + e1;
      #pragma unroll
      for (int off = 8; off; off >>= 1) se += __shfl_xor(se, off);
      float inv = 1.f / se;
      e0 *= inv; e1 *= inv;
      sS2[n * 33 + j0] = e0;
      sS2[n * 33 + j0 + 1] = e1;
      ws[WS_S2 + (size_t)(b * 64 + n) * 32 + j0] = e0;
      ws[WS_S2 + (size_t)(b * 64 + n) * 32 + j0 + 1] = e1;
    }
    __syncthreads();
    if (tid < 64) {
      float s = 0.f;
      for (int m = 0; m < 64; ++m) s += sA2[tid * 65 + m];
      sdf[tid] = s;
    }
    // sT = adj1 @ S2 : 2 outputs/thread
    {
      int n2 = tid >> 4, j0 = (tid & 15) * 2;
      float t0 = 0.f, t1 = 0.f;
      for (int m = 0; m < 64; ++m) {
        float a = sA2[n2 * 65 + m];
        t0 += a * sS2[m * 33 + j0];
        t1 += a * sS2[m * 33 + j0 + 1];
      }
      sT[n2 * 33 + j0] = t0;
      sT[n2 * 33 + j0 + 1] = t1;
    }
    float accD = 0.f;
    if (tid < 64) {
      float t = 0.f;
      for (int q = 0; q < 32; ++q) { float v = sS2[tid * 33 + q]; t += v * v; }
      accD = t * sdf[tid];
    }
    __syncthreads();
    // oa/ss: 1 output/thread (32x32)
    int k5 = tid >> 5, j5 = tid & 31;
    float accA = 0.f, accS = 0.f;
    for (int n3 = 0; n3 < 64; ++n3) {
      float sk = sS2[n3 * 33 + k5];
      accA += sk * sT[n3 * 33 + j5];
      accS += sk * sS2[n3 * 33 + j5];
    }
    oaL[k5 * 33 + j5] = accA;
    ssL[k5 * 33 + j5] = accS;
    float fro2p = accS * accS;
    __syncthreads();
    float num = 0.f, trs = 0.f;
    if (tid < 32) {
      num = oaL[tid * 33 + tid];
      trs = ssL[tid * 33 + tid];
      float rs = 0.f;
      for (int j = 0; j < 32; ++j) rs += oaL[tid * 33 + j];
      ddL[tid] = sqrtf(fmaxf(rs - num, 0.f)) + 1e-15f;
    }
    float numT = blockRedSum16(num, red);
    float denT = blockRedSum16(accD, red);
    float froT = sqrtf(blockRedSum16(fro2p, red));
    float trT = blockRedSum16(trs, red);
    {
      float dk = ddL[k5];
      float* a2 = ws + WS_ADJ2 + (size_t)b * 1024;
      a2[k5 * 32 + j5] = (k5 == j5) ? 0.f : oaL[k5 * 33 + j5] / (dk * ddL[j5]);
    }
    if (tid == 0) {
      ws[WS_SCAL + 32 + b] = numT / denT;
      ws[WS_SCAL + 48 + b] = sqrtf(fmaxf(2.f - 2.f * trT / (5.656854249f * froT), 0.f));
    }
  }
  gridBarrier(bar);

  // ---------------- Phase 67: x3+conv3 in-LDS (blks 0..127) + agg (128..255)
  if (blk < 128) {
    int bt = blk, b = bt >> 3;
    float* sX  = sm;            // 64*65 = 4160 (X2[bt])
    float* sS  = sm + 4160;     // 64*33 = 2112 (S2[b])
    float* sX3 = sm + 6272;     // 32*65 = 2080
    float* sA  = sm + 8352;     // 32*33 = 1056 (ADJ2[b])
    float* sY  = sm + 9408;     // 32*65 = 2080
    float* sWr = sm + 11488;    // 4160
    float* sWs = sm + 15648;    // 4160 -> 19808
    for (int idx = tid; idx < 4096; idx += 1024)
      sX[(idx >> 6) * 65 + (idx & 63)] = ws[WS_X2 + (size_t)bt * 4096 + idx];
    for (int idx = tid; idx < 2048; idx += 1024)
      sS[(idx >> 5) * 33 + (idx & 31)] = ws[WS_S2 + (size_t)b * 2048 + idx];
    sA[(tid >> 5) * 33 + (tid & 31)] = ws[WS_ADJ2 + (size_t)b * 1024 + tid];
    for (int idx = tid; idx < 4096; idx += 1024) {
      int r = idx >> 6, c = idx & 63;
      sWr[r * 65 + c] = c3rW[idx];
      sWs[r * 65 + c] = c3sW[idx];
    }
    __syncthreads();
    int k = tid >> 5, h0 = (tid & 31) * 2;
    // x3[k][h] = sum_n S2[n][k] * X2[n][h]
    float a0 = 0.f, a1 = 0.f;
    for (int n = 0; n < 64; ++n) {
      float sv = sS[n * 33 + k];
      a0 += sv * sX[n * 65 + h0];
      a1 += sv * sX[n * 65 + h0 + 1];
    }
    sX3[k * 65 + h0] = a0;
    sX3[k * 65 + h0 + 1] = a1;
    __syncthreads();
    // Y[k][h] = sum_m A2[k][m] * X3[m][h]  (m < 32)
    a0 = 0.f; a1 = 0.f;
    for (int m = 0; m < 32; ++m) {
      float a = sA[k * 33 + m];
      a0 += a * sX3[m * 65 + h0];
      a1 += a * sX3[m * 65 + h0 + 1];
    }
    sY[k * 65 + h0] = a0;
    sY[k * 65 + h0 + 1] = a1;
    __syncthreads();
    // out[k][h] = b + sum_m Y[k][m]*Wr[m][h] + X3[k][m]*Ws[m][h]  (m < 64)
    a0 = c3rb[h0]; a1 = c3rb[h0 + 1];
    for (int m = 0; m < 64; ++m) {
      float y = sY[k * 65 + m], x = sX3[k * 65 + m];
      a0 += y * sWr[m * 65 + h0] + x * sWs[m * 65 + h0];
      a1 += y * sWr[m * 65 + h0 + 1] + x * sWs[m * 65 + h0 + 1];
    }
    out[(size_t)bt * 2048 + k * 64 + h0] = a0;
    out[(size_t)bt * 2048 + k * 64 + h0 + 1] = a1;
  } else {
    int rb = blk - 128;
    int b = rb >> 3, sub = rb & 7;
    float* sS = sm;  // 64*33
    for (int idx = tid; idx < 2048; idx += 1024)
      sS[(idx >> 5) * 33 + (idx & 31)] = ws[WS_S2 + (size_t)b * 2048 + idx];
    __syncthreads();
    int n = sub * 32 + (tid >> 5), j = tid & 31;
    const float* s1r = ws + WS_S1 + ((size_t)((b << 8) + n)) * 64;
    float acc = 0.f;
    #pragma unroll 4
    for (int kq = 0; kq < 64; ++kq) acc += s1r[kq] * sS[kq * 33 + j];
    out[262146 + ((size_t)((b << 8) + n)) * 32 + j] = acc;
    if (blk == 255 && tid == 0) {
      float mc = 0.f, o = 0.f;
      #pragma unroll
      for (int b2 = 0; b2 < 16; ++b2) {
        mc += ws[WS_SCAL + b2] + ws[WS_SCAL + 32 + b2];
        o += ws[WS_SCAL + 16 + b2] + ws[WS_SCAL + 48 + b2];
      }
      out[262144] = -mc / 16.0f;
      out[262145] = o / 16.0f;
    }
  }
}

// ================================================================ launch
extern "C" void kernel_launch(void* const* d_in, const int* in_sizes, int n_in,
                              void* d_out, int out_size, void* d_ws, size_t ws_size,
                              hipStream_t stream) {
  (void)in_sizes; (void)n_in; (void)out_size; (void)ws_size;
  const float* pos = (const float*)d_in[0];
  const int* ei = (const int*)d_in[1];
  const float* ea = (const float*)d_in[2];
  const float* W1 = (const float*)d_in[4];
  const float* b1 = (const float*)d_in[5];
  const float* p1W = (const float*)d_in[6];
  const float* p1b = (const float*)d_in[7];
  const float* c2rW = (const float*)d_in[8];
  const float* c2rb = (const float*)d_in[9];
  const float* c2sW = (const float*)d_in[10];
  const float* p2W = (const float*)d_in[11];
  const float* p2b = (const float*)d_in[12];
  const float* c3rW = (const float*)d_in[13];
  const float* c3rb = (const float*)d_in[14];
  const float* c3sW = (const float*)d_in[15];
  float* ws = (float*)d_ws;
  float* out = (float*)d_out;

  // zero WadjT+Adn+wsum (8.4 MB) and the barrier state (capture-legal)
  hipMemsetAsync(d_ws, 0, (size_t)2101248 * sizeof(float), stream);
  hipMemsetAsync((char*)d_ws + (size_t)WS_BAR * sizeof(float), 0, 4608, stream);
  k_mega<<<dim3(NBLK), dim3(1024), 0, stream>>>(
      pos, ei, ea, W1, b1, p1W, p1b, c2rW, c2rb, c2sW,
      p2W, p2b, c3rW, c3rb, c3sW, ws, out);
}

// Round 14
// 261.218 us; speedup vs baseline: 2.0299x; 1.3771x over previous
//
#include <hip/hip_runtime.h>
#include <cstdint>

// v4: 7-kernel train of R11-validated phase bodies, verbatim — every
// in-kernel gridBarrier (measured ~38us each, fence-floor) replaced by a
// kernel boundary (measured ~10-12us, HW-managed coherence).
//  memset(8.4MB)                         zero WadjT/Adn/wsum
//  k_p0      <<<256,1024>>>  16KB LDS    XW = pos@W1 + edge scatter + wsum
//  k_gcn_s1  <<<256,1024>>>  31KB LDS    GCN+relu -> H + fused s1
//  k_as1     <<<256,1024>>>  32KB LDS    AS1 (1 node/wave) + dflat
//  k_pool1x1 <<<144,1024>>>  21KB LDS    pool1 (blk<16) + x1 (blk 16..143)
//  k_conv2   <<<128,1024>>>  83KB LDS    conv2
//  k_s2pool2 <<<16,1024>>>   67KB LDS    s2 + pool2
//  k_final   <<<256,1024>>>  79KB LDS    x3+conv3 (blk<128) + agg + losses

#define WS_WADJT 0
#define WS_ADN   1048576
#define WS_WSUM  2097152
#define WS_XW    2101248
#define WS_H     4198400
#define WS_S1    6295552
#define WS_TMP   6557696
#define WS_DFLAT 6819840
#define WS_ADJ1  6823936
#define WS_X1    6889472
#define WS_X2    7413760
#define WS_S2    8200192
#define WS_ADJ2  8232960
#define WS_SCAL  8249344

// 1024-thread (16-wave) block reduction, red[16]
__device__ __forceinline__ float blockRedSum16(float v, float* red) {
  #pragma unroll
  for (int m = 32; m; m >>= 1) v += __shfl_xor(v, m);
  __syncthreads();
  if ((threadIdx.x & 63) == 0) red[threadIdx.x >> 6] = v;
  __syncthreads();
  float s = 0.f;
  #pragma unroll
  for (int i = 0; i < 16; ++i) s += red[i];
  __syncthreads();
  return s;
}

// ---------------- K1: XW = pos @ W1 ; edge scatter + wsum
__global__ __launch_bounds__(1024) void k_p0(const float* __restrict__ pos,
                                             const int* __restrict__ ei,
                                             const float* __restrict__ ea,
                                             const float* __restrict__ W1,
                                             float* __restrict__ ws) {
  __shared__ float sm[4096];
  int tid = threadIdx.x, blk = blockIdx.x;
  for (int i = tid; i < 4096; i += 1024) sm[i] = W1[i];
  __syncthreads();
  int col = tid & 63;
  #pragma unroll
  for (int pass = 0; pass < 8; ++pass) {
    int row = blk * 128 + pass * 16 + (tid >> 6);
    const float* a = pos + (size_t)row * 64;
    float acc = 0.f;
    #pragma unroll 8
    for (int k = 0; k < 64; ++k) acc += a[k] * sm[k * 64 + col];
    ws[WS_XW + (size_t)row * 64 + col] = acc;
  }
  if (tid < 256) {
    int e = blk * 256 + tid;
    int s = ei[e], d = ei[65536 + e];
    int g = s >> 8, r = s & 255, c = d & 255;
    float w = ea[e];
    atomicAdd(&ws[WS_WADJT + (size_t)(((g << 8) + c) << 8) + r], w);
    atomicAdd(&ws[WS_ADN + (size_t)(((g << 8) + r) << 8) + c], 1.0f);
    atomicAdd(&ws[WS_WSUM + (g << 8) + c], w);
  }
}

// ---------------- K2: GCN + relu -> H ; fused s1 (4 nodes x 4 iters)
__global__ __launch_bounds__(1024) void k_gcn_s1(float* __restrict__ ws,
                                                 const float* __restrict__ b1,
                                                 const float* __restrict__ p1W,
                                                 const float* __restrict__ p1b) {
  __shared__ float sm[7696];
  int tid = threadIdx.x, blk = blockIdx.x;
  float* sW = sm;                 // 4096 (p1W)
  float* dinvL = sm + 4096;       // 256
  float* pL = sm + 4352;          // 1024
  float* red4 = sm + 5376;        // 1024
  float* xm = sm + 6400;          // 256 (4 x 64)
  int* iL = (int*)(sm + 6656);    // 1024 ints
  int* wcnt = (int*)(sm + 7680);  // 16 ints
  int g = blk >> 4;
  for (int i = tid; i < 4096; i += 1024) sW[i] = p1W[i];
  if (tid < 256) dinvL[tid] = rsqrtf(ws[WS_WSUM + (g << 8) + tid] + 1.0f);
  __syncthreads();
  int ng = tid >> 8, ltid = tid & 255, lw = (tid >> 6) & 3, lane = tid & 63;
  float bb = b1[ltid & 63];
  for (int it = 0; it < 4; ++it) {
    int n = blk * 16 + it * 4 + ng;
    int cc = n & 255;
    float dn = dinvL[cc];
    float pv = ws[WS_WADJT + (size_t)n * 256 + ltid] * dinvL[ltid] * dn;
    if (ltid == cc) pv += dn * dn;
    bool act = (pv != 0.f);
    unsigned long long mask = __ballot(act);
    int wpos = (int)__popcll(mask & ((1ull << lane) - 1ull));
    if (lane == 0) wcnt[ng * 4 + lw] = (int)__popcll(mask);
    __syncthreads();
    int base = 0;
    #pragma unroll
    for (int i = 0; i < 4; ++i) base += (i < lw) ? wcnt[ng * 4 + i] : 0;
    int na = wcnt[ng * 4] + wcnt[ng * 4 + 1] + wcnt[ng * 4 + 2] + wcnt[ng * 4 + 3];
    if (act) { iL[ng * 256 + base + wpos] = ltid; pL[ng * 256 + base + wpos] = pv; }
    __syncthreads();
    const float* xg = ws + WS_XW + (size_t)g * 131072;
    float acc0 = 0.f, acc1 = 0.f;
    #pragma unroll 4
    for (int i = 0; i < na; ++i) {
      int r = iL[ng * 256 + i];
      float p = pL[ng * 256 + i];
      acc0 += p * xg[(size_t)r * 512 + ltid];
      acc1 += p * xg[(size_t)r * 512 + 256 + ltid];
    }
    acc0 = fmaxf(acc0 + bb, 0.f);
    acc1 = fmaxf(acc1 + bb, 0.f);
    float* hp = ws + WS_H + (size_t)n * 512;
    hp[ltid] = acc0;
    hp[256 + ltid] = acc1;
    red4[ng * 256 + lw * 64 + (ltid & 63)] = acc0 + acc1;
    __syncthreads();
    if (ltid < 64) {
      xm[ng * 64 + ltid] = 0.125f * (red4[ng * 256 + ltid] + red4[ng * 256 + 64 + ltid] +
                                     red4[ng * 256 + 128 + ltid] + red4[ng * 256 + 192 + ltid]);
      float a = p1b[ltid];
      #pragma unroll 4
      for (int kq = 0; kq < 64; ++kq) a += xm[ng * 64 + kq] * sW[kq * 64 + ltid];
      float v = tanhf(a);
      float mx = v;
      #pragma unroll
      for (int m = 32; m; m >>= 1) mx = fmaxf(mx, __shfl_xor(mx, m));
      float e = __expf(v - mx);
      float se = e;
      #pragma unroll
      for (int m = 32; m; m >>= 1) se += __shfl_xor(se, m);
      ws[WS_S1 + (size_t)n * 64 + ltid] = e / se;
    }
    __syncthreads();
  }
}

// ---------------- K3: AS1 = Adn @ S1 (1 node per wave) + dflat
__global__ __launch_bounds__(1024) void k_as1(float* __restrict__ ws) {
  __shared__ float sm[8192];
  int tid = threadIdx.x, blk = blockIdx.x;
  float* aL = sm;                 // 4096
  int* iLa = (int*)(sm + 4096);   // 4096 ints
  int w = tid >> 6, lane = tid & 63;
  int n = blk * 16 + w;
  int g = n >> 8;
  float4 av = *(const float4*)(ws + WS_ADN + (size_t)n * 256 + lane * 4);
  float rs = av.x + av.y + av.z + av.w;
  #pragma unroll
  for (int m = 32; m; m >>= 1) rs += __shfl_xor(rs, m);
  if (lane == 0) ws[WS_DFLAT + n] = rs;
  float avv[4] = {av.x, av.y, av.z, av.w};
  unsigned long long below = (1ull << lane) - 1ull;
  int base = 0;
  #pragma unroll
  for (int q = 0; q < 4; ++q) {
    bool act = (avv[q] != 0.f);
    unsigned long long mask = __ballot(act);
    if (act) {
      int p = base + (int)__popcll(mask & below);
      iLa[w * 256 + p] = lane * 4 + q;
      aL[w * 256 + p] = avv[q];
    }
    base += (int)__popcll(mask);
  }
  int na = base;
  float acc = 0.f;
  const float* S1g = ws + WS_S1 + ((size_t)g << 8) * 64;
  #pragma unroll 4
  for (int i = 0; i < na; ++i) {
    int m = iLa[w * 256 + i];
    float a = aL[w * 256 + i];
    acc += a * S1g[(size_t)m * 64 + lane];
  }
  ws[WS_TMP + (size_t)n * 64 + lane] = acc;
}

// ---------------- K4: pool1 (blks 0..15) + x1 (blks 16..143)
__global__ __launch_bounds__(1024) void k_pool1x1(float* __restrict__ ws) {
  __shared__ float sm[5328];
  int tid = threadIdx.x, blk = blockIdx.x;
  if (blk < 16) {
    int b = blk;
    float* S1c = sm;          // 2048
    float* Tc = sm + 2048;    // 2048
    float* prs = sm + 4096;   // 64*17 = 1088
    float* diagL = sm + 5184; // 64
    float* dd = sm + 5248;    // 64
    float* red = sm + 5312;   // 16
    const float* Sb = ws + WS_S1 + (size_t)b * 16384;
    const float* Tb = ws + WS_TMP + (size_t)b * 16384;
    int k = tid >> 4, j0 = (tid & 15) * 4;
    float accA[4] = {0, 0, 0, 0}, accS[4] = {0, 0, 0, 0};
    for (int n0 = 0; n0 < 256; n0 += 32) {
      __syncthreads();
      S1c[tid] = Sb[n0 * 64 + tid];
      S1c[tid + 1024] = Sb[n0 * 64 + 1024 + tid];
      Tc[tid] = Tb[n0 * 64 + tid];
      Tc[tid + 1024] = Tb[n0 * 64 + 1024 + tid];
      __syncthreads();
      for (int i = 0; i < 32; ++i) {
        float sk = S1c[i * 64 + k];
        float4 tv = *(const float4*)(Tc + i * 64 + j0);
        float4 sv = *(const float4*)(S1c + i * 64 + j0);
        accA[0] += sk * tv.x; accA[1] += sk * tv.y; accA[2] += sk * tv.z; accA[3] += sk * tv.w;
        accS[0] += sk * sv.x; accS[1] += sk * sv.y; accS[2] += sk * sv.z; accS[3] += sk * sv.w;
      }
    }
    float num = 0.f, fro2 = 0.f, rsp = 0.f;
    #pragma unroll
    for (int q = 0; q < 4; ++q) { rsp += accA[q]; fro2 += accS[q] * accS[q]; }
    if (k >= j0 && k < j0 + 4) { num = accA[k - j0]; diagL[k] = accA[k - j0]; }
    prs[k * 17 + (tid & 15)] = rsp;
    __syncthreads();
    if (tid < 64) {
      float rs = 0.f;
      #pragma unroll
      for (int i = 0; i < 16; ++i) rs += prs[tid * 17 + i];
      dd[tid] = sqrtf(fmaxf(rs - diagL[tid], 0.f)) + 1e-15f;
    }
    float denp = 0.f;
    if (tid < 256) {
      const float* s = Sb + tid * 64;
      float qq = 0.f;
      for (int kk = 0; kk < 64; kk += 4) {
        float4 v = *(const float4*)(s + kk);
        qq += v.x * v.x + v.y * v.y + v.z * v.z + v.w * v.w;
      }
      denp = qq * ws[WS_DFLAT + (b << 8) + tid];
    }
    float numT = blockRedSum16(num, red);
    float denT = blockRedSum16(denp, red);
    float froT = sqrtf(blockRedSum16(fro2, red));
    float inv_fro = 1.f / froT;
    float osum = 0.f;
    #pragma unroll
    for (int q = 0; q < 4; ++q) {
      float v = accS[q] * inv_fro - ((j0 + q) == k ? 0.125f : 0.f);
      osum += v * v;
    }
    float orT = blockRedSum16(osum, red);
    float* adj = ws + WS_ADJ1 + (size_t)b * 4096;
    float dk = dd[k];
    #pragma unroll
    for (int q = 0; q < 4; ++q) {
      int j = j0 + q;
      adj[k * 64 + j] = (k == j) ? 0.f : accA[q] / (dk * dd[j]);
    }
    if (tid == 0) {
      ws[WS_SCAL + b] = numT / denT;
      ws[WS_SCAL + 16 + b] = sqrtf(orT);
    }
  } else {
    // x1[b,t,k,h] = sum_n S1[b,n,k] h[b,n,t,h]
    int bt = blk - 16;
    int b = bt >> 3, t = bt & 7;
    int hc = tid & 63, kb = (tid >> 6) * 4;
    float* sS = sm;          // 2048
    float* sX = sm + 2048;   // 2048
    float acc[4] = {0, 0, 0, 0};
    for (int n0 = 0; n0 < 256; n0 += 32) {
      __syncthreads();
      for (int idx = tid; idx < 2048; idx += 1024) {
        int i = idx >> 6, c = idx & 63;
        sS[idx] = ws[WS_S1 + ((size_t)((b << 8) + n0 + i)) * 64 + c];
        sX[idx] = ws[WS_H + ((size_t)((b << 8) + n0 + i)) * 512 + t * 64 + c];
      }
      __syncthreads();
      for (int i = 0; i < 32; ++i) {
        float xv = sX[i * 64 + hc];
        #pragma unroll
        for (int q = 0; q < 4; ++q) acc[q] += sS[i * 64 + kb + q] * xv;
      }
    }
    #pragma unroll
    for (int q = 0; q < 4; ++q)
      ws[WS_X1 + ((size_t)bt * 64 + kb + q) * 64 + hc] = acc[q];
  }
}

// ---------------- K5: conv2 (128 blocks)
__global__ __launch_bounds__(1024) void k_conv2(float* __restrict__ ws,
                                                const float* __restrict__ c2rW,
                                                const float* __restrict__ c2rb,
                                                const float* __restrict__ c2sW) {
  __shared__ float sm[20800];
  int tid = threadIdx.x, blk = blockIdx.x;
  int bt = blk;
  int b = bt >> 3;
  float* sA = sm;
  float* sX = sm + 4160;
  float* sY = sm + 8320;
  float* sWr = sm + 12480;
  float* sWs = sm + 16640;
  for (int idx = tid; idx < 4096; idx += 1024) {
    int r = idx >> 6, c = idx & 63;
    sA[r * 65 + c] = ws[WS_ADJ1 + (size_t)b * 4096 + idx];
    sX[r * 65 + c] = ws[WS_X1 + (size_t)bt * 4096 + idx];
    sWr[r * 65 + c] = c2rW[idx];
    sWs[r * 65 + c] = c2sW[idx];
  }
  __syncthreads();
  int n = tid >> 4, h0 = (tid & 15) * 4;
  float acc[4];
  #pragma unroll
  for (int q = 0; q < 4; ++q) acc[q] = 0.f;
  for (int m = 0; m < 64; ++m) {
    float a = sA[n * 65 + m];
    #pragma unroll
    for (int q = 0; q < 4; ++q) acc[q] += a * sX[m * 65 + h0 + q];
  }
  #pragma unroll
  for (int q = 0; q < 4; ++q) sY[n * 65 + h0 + q] = acc[q];
  __syncthreads();
  #pragma unroll
  for (int q = 0; q < 4; ++q) acc[q] = c2rb[h0 + q];
  for (int m = 0; m < 64; ++m) {
    float y = sY[n * 65 + m], x = sX[n * 65 + m];
    #pragma unroll
    for (int q = 0; q < 4; ++q)
      acc[q] += y * sWr[m * 65 + h0 + q] + x * sWs[m * 65 + h0 + q];
  }
  #pragma unroll
  for (int q = 0; q < 4; ++q)
    ws[WS_X2 + (size_t)bt * 4096 + n * 64 + h0 + q] = fmaxf(acc[q], 0.f);
}

// ---------------- K6: s2 (in LDS) + pool2 fused (16 blocks)
__global__ __launch_bounds__(1024) void k_s2pool2(float* __restrict__ ws,
                                                  const float* __restrict__ p2W,
                                                  const float* __restrict__ p2b) {
  __shared__ float sm[16752];
  int tid = threadIdx.x;
  int b = blockIdx.x;
  float* xmL = sm;            // 4096
  float* sS2 = sm + 4096;     // 64*33 = 2112
  float* sA2 = sm + 6208;     // 64*65 = 4160
  float* sT  = sm + 10368;    // 64*33 = 2112
  float* oaL = sm + 12480;    // 32*33 = 1056
  float* ssL = sm + 13536;    // 32*33 = 1056
  float* sdf = sm + 14592;    // 64
  float* ddL = sm + 14656;    // 32
  float* red = sm + 14688;    // 16
  float* sp2W = sm + 14704;   // 2048
  for (int idx = tid; idx < 4096; idx += 1024)
    sA2[(idx >> 6) * 65 + (idx & 63)] = ws[WS_ADJ1 + (size_t)b * 4096 + idx];
  for (int idx = tid; idx < 2048; idx += 1024) sp2W[idx] = p2W[idx];
  for (int idx = tid; idx < 4096; idx += 1024) {
    int n = idx >> 6, f = idx & 63;
    float s = 0.f;
    #pragma unroll
    for (int t = 0; t < 8; ++t)
      s += ws[WS_X2 + ((size_t)(b * 8 + t) * 64 + n) * 64 + f];
    xmL[idx] = s * 0.125f;
  }
  __syncthreads();
  {
    int n = tid >> 4, j0 = (tid & 15) * 2;
    float a0 = p2b[j0], a1 = p2b[j0 + 1];
    for (int kq = 0; kq < 64; ++kq) {
      float v = xmL[n * 64 + kq];
      a0 += v * sp2W[kq * 32 + j0];
      a1 += v * sp2W[kq * 32 + j0 + 1];
    }
    float v0 = tanhf(a0), v1 = tanhf(a1);
    float mx = fmaxf(v0, v1);
    #pragma unroll
    for (int off = 8; off; off >>= 1) mx = fmaxf(mx, __shfl_xor(mx, off));
    float e0 = __expf(v0 - mx), e1 = __expf(v1 - mx);
    float se = e0 + e1;
    #pragma unroll
    for (int off = 8; off; off >>= 1) se += __shfl_xor(se, off);
    float inv = 1.f / se;
    e0 *= inv; e1 *= inv;
    sS2[n * 33 + j0] = e0;
    sS2[n * 33 + j0 + 1] = e1;
    ws[WS_S2 + (size_t)(b * 64 + n) * 32 + j0] = e0;
    ws[WS_S2 + (size_t)(b * 64 + n) * 32 + j0 + 1] = e1;
  }
  __syncthreads();
  if (tid < 64) {
    float s = 0.f;
    for (int m = 0; m < 64; ++m) s += sA2[tid * 65 + m];
    sdf[tid] = s;
  }
  {
    int n2 = tid >> 4, j0 = (tid & 15) * 2;
    float t0 = 0.f, t1 = 0.f;
    for (int m = 0; m < 64; ++m) {
      float a = sA2[n2 * 65 + m];
      t0 += a * sS2[m * 33 + j0];
      t1 += a * sS2[m * 33 + j0 + 1];
    }
    sT[n2 * 33 + j0] = t0;
    sT[n2 * 33 + j0 + 1] = t1;
  }
  float accD = 0.f;
  if (tid < 64) {
    float t = 0.f;
    for (int q = 0; q < 32; ++q) { float v = sS2[tid * 33 + q]; t += v * v; }
    accD = t * sdf[tid];
  }
  __syncthreads();
  int k5 = tid >> 5, j5 = tid & 31;
  float accA = 0.f, accS = 0.f;
  for (int n3 = 0; n3 < 64; ++n3) {
    float sk = sS2[n3 * 33 + k5];
    accA += sk * sT[n3 * 33 + j5];
    accS += sk * sS2[n3 * 33 + j5];
  }
  oaL[k5 * 33 + j5] = accA;
  ssL[k5 * 33 + j5] = accS;
  float fro2p = accS * accS;
  __syncthreads();
  float num = 0.f, trs = 0.f;
  if (tid < 32) {
    num = oaL[tid * 33 + tid];
    trs = ssL[tid * 33 + tid];
    float rs = 0.f;
    for (int j = 0; j < 32; ++j) rs += oaL[tid * 33 + j];
    ddL[tid] = sqrtf(fmaxf(rs - num, 0.f)) + 1e-15f;
  }
  float numT = blockRedSum16(num, red);
  float denT = blockRedSum16(accD, red);
  float froT = sqrtf(blockRedSum16(fro2p, red));
  float trT = blockRedSum16(trs, red);
  {
    float dk = ddL[k5];
    float* a2 = ws + WS_ADJ2 + (size_t)b * 1024;
    a2[k5 * 32 + j5] = (k5 == j5) ? 0.f : oaL[k5 * 33 + j5] / (dk * ddL[j5]);
  }
  if (tid == 0) {
    ws[WS_SCAL + 32 + b] = numT / denT;
    ws[WS_SCAL + 48 + b] = sqrtf(fmaxf(2.f - 2.f * trT / (5.656854249f * froT), 0.f));
  }
}

// ---------------- K7: x3+conv3 in-LDS (blks 0..127) + agg (128..255) + losses
__global__ __launch_bounds__(1024) void k_final(float* __restrict__ ws,
                                                const float* __restrict__ c3rW,
                                                const float* __restrict__ c3rb,
                                                const float* __restrict__ c3sW,
                                                float* __restrict__ out) {
  __shared__ float sm[19808];
  int tid = threadIdx.x, blk = blockIdx.x;
  if (blk < 128) {
    int bt = blk, b = bt >> 3;
    float* sX  = sm;            // 64*65 = 4160 (X2[bt])
    float* sS  = sm + 4160;     // 64*33 = 2112 (S2[b])
    float* sX3 = sm + 6272;     // 32*65 = 2080
    float* sA  = sm + 8352;     // 32*33 = 1056 (ADJ2[b])
    float* sY  = sm + 9408;     // 32*65 = 2080
    float* sWr = sm + 11488;    // 4160
    float* sWs = sm + 15648;    // 4160 -> 19808
    for (int idx = tid; idx < 4096; idx += 1024)
      sX[(idx >> 6) * 65 + (idx & 63)] = ws[WS_X2 + (size_t)bt * 4096 + idx];
    for (int idx = tid; idx < 2048; idx += 1024)
      sS[(idx >> 5) * 33 + (idx & 31)] = ws[WS_S2 + (size_t)b * 2048 + idx];
    sA[(tid >> 5) * 33 + (tid & 31)] = ws[WS_ADJ2 + (size_t)b * 1024 + tid];
    for (int idx = tid; idx < 4096; idx += 1024) {
      int r = idx >> 6, c = idx & 63;
      sWr[r * 65 + c] = c3rW[idx];
      sWs[r * 65 + c] = c3sW[idx];
    }
    __syncthreads();
    int k = tid >> 5, h0 = (tid & 31) * 2;
    // x3[k][h] = sum_n S2[n][k] * X2[n][h]
    float a0 = 0.f, a1 = 0.f;
    for (int n = 0; n < 64; ++n) {
      float sv = sS[n * 33 + k];
      a0 += sv * sX[n * 65 + h0];
      a1 += sv * sX[n * 65 + h0 + 1];
    }
    sX3[k * 65 + h0] = a0;
    sX3[k * 65 + h0 + 1] = a1;
    __syncthreads();
    // Y[k][h] = sum_m A2[k][m] * X3[m][h]  (m < 32)
    a0 = 0.f; a1 = 0.f;
    for (int m = 0; m < 32; ++m) {
      float a = sA[k * 33 + m];
      a0 += a * sX3[m * 65 + h0];
      a1 += a * sX3[m * 65 + h0 + 1];
    }
    sY[k * 65 + h0] = a0;
    sY[k * 65 + h0 + 1] = a1;
    __syncthreads();
    // out[k][h] = b + sum_m Y[k][m]*Wr[m][h] + X3[k][m]*Ws[m][h]  (m < 64)
    a0 = c3rb[h0]; a1 = c3rb[h0 + 1];
    for (int m = 0; m < 64; ++m) {
      float y = sY[k * 65 + m], x = sX3[k * 65 + m];
      a0 += y * sWr[m * 65 + h0] + x * sWs[m * 65 + h0];
      a1 += y * sWr[m * 65 + h0 + 1] + x * sWs[m * 65 + h0 + 1];
    }
    out[(size_t)bt * 2048 + k * 64 + h0] = a0;
    out[(size_t)bt * 2048 + k * 64 + h0 + 1] = a1;
  } else {
    int rb = blk - 128;
    int b = rb >> 3, sub = rb & 7;
    float* sS = sm;  // 64*33
    for (int idx = tid; idx < 2048; idx += 1024)
      sS[(idx >> 5) * 33 + (idx & 31)] = ws[WS_S2 + (size_t)b * 2048 + idx];
    __syncthreads();
    int n = sub * 32 + (tid >> 5), j = tid & 31;
    const float* s1r = ws + WS_S1 + ((size_t)((b << 8) + n)) * 64;
    float acc = 0.f;
    #pragma unroll 4
    for (int kq = 0; kq < 64; ++kq) acc += s1r[kq] * sS[kq * 33 + j];
    out[262146 + ((size_t)((b << 8) + n)) * 32 + j] = acc;
    if (blk == 255 && tid == 0) {
      float mc = 0.f, o = 0.f;
      #pragma unroll
      for (int b2 = 0; b2 < 16; ++b2) {
        mc += ws[WS_SCAL + b2] + ws[WS_SCAL + 32 + b2];
        o += ws[WS_SCAL + 16 + b2] + ws[WS_SCAL + 48 + b2];
      }
      out[262144] = -mc / 16.0f;
      out[262145] = o / 16.0f;
    }
  }
}

// ================================================================ launch
extern "C" void kernel_launch(void* const* d_in, const int* in_sizes, int n_in,
                              void* d_out, int out_size, void* d_ws, size_t ws_size,
                              hipStream_t stream) {
  (void)in_sizes; (void)n_in; (void)out_size; (void)ws_size;
  const float* pos = (const float*)d_in[0];
  const int* ei = (const int*)d_in[1];
  const float* ea = (const float*)d_in[2];
  const float* W1 = (const float*)d_in[4];
  const float* b1 = (const float*)d_in[5];
  const float* p1W = (const float*)d_in[6];
  const float* p1b = (const float*)d_in[7];
  const float* c2rW = (const float*)d_in[8];
  const float* c2rb = (const float*)d_in[9];
  const float* c2sW = (const float*)d_in[10];
  const float* p2W = (const float*)d_in[11];
  const float* p2b = (const float*)d_in[12];
  const float* c3rW = (const float*)d_in[13];
  const float* c3rb = (const float*)d_in[14];
  const float* c3sW = (const float*)d_in[15];
  float* ws = (float*)d_ws;
  float* out = (float*)d_out;

  // zero WadjT+Adn+wsum (8.4 MB)
  hipMemsetAsync(d_ws, 0, (size_t)2101248 * sizeof(float), stream);
  k_p0<<<dim3(256), dim3(1024), 0, stream>>>(pos, ei, ea, W1, ws);
  k_gcn_s1<<<dim3(256), dim3(1024), 0, stream>>>(ws, b1, p1W, p1b);
  k_as1<<<dim3(256), dim3(1024), 0, stream>>>(ws);
  k_pool1x1<<<dim3(144), dim3(1024), 0, stream>>>(ws);
  k_conv2<<<dim3(128), dim3(1024), 0, stream>>>(ws, c2rW, c2rb, c2sW);
  k_s2pool2<<<dim3(16), dim3(1024), 0, stream>>>(ws, p2W, p2b);
  k_final<<<dim3(256), dim3(1024), 0, stream>>>(ws, c3rW, c3rb, c3sW, out);
}